// Round 16
// baseline (670.835 us; speedup 1.0000x reference)
//
#include <hip/hip_runtime.h>
#include <math.h>

#define B_ 4
#define N_ 16384
#define M_ 1024
#define C_ 64

// output layout (floats): new_xyz [B*M*3] | feats [B*256*M] | inds [B*M]
#define OUT_XYZ_ELEMS (B_ * M_ * 3)
#define OUT_FEAT_ELEMS (B_ * 256 * M_)
#define PST 1024  // partial-stats stride (>= max j-blocks)

typedef __attribute__((ext_vector_type(8))) short bf16x8;
typedef __attribute__((ext_vector_type(4))) float f32x4;
typedef __attribute__((address_space(1))) const void gk_gvoid;
typedef __attribute__((address_space(3))) void gk_svoid;

__device__ __forceinline__ unsigned short f2bf(float f) {
    unsigned int u = __float_as_uint(f);
    u += 0x7fffu + ((u >> 16) & 1u);
    return (unsigned short)(u >> 16);
}
__device__ __forceinline__ float bf2f(unsigned short h) {
    return __uint_as_float(((unsigned int)h) << 16);
}
// hardware packed f32x2 -> bf16x2 (RNE), src0 -> low half
__device__ __forceinline__ unsigned int cvt_pk(float lo, float hi) {
    unsigned int r;
    asm("v_cvt_pk_bf16_f32 %0, %1, %2" : "=v"(r) : "v"(lo), "v"(hi));
    return r;
}

// ------------------------------------------------------------------
// block-cooperative BN finalize: reduce per-block partials -> scale/shift.
// mode 0: ss = (scale, shift/scale); mode 1: ss = (scale, shift).
__device__ __forceinline__ void fin_block(const float* pS, const float* pS2,
                                          const float* g, const float* bt,
                                          float* ss, int cout, int gx, float invN, int mode) {
    int tid = threadIdx.x, lane = tid & 63, wv = tid >> 6;
    for (int o = wv; o < cout; o += 4) {
        float s = 0.f, s2 = 0.f;
        for (int i = lane; i < gx; i += 64) {
            s += pS[(size_t)o * PST + i];
            s2 += pS2[(size_t)o * PST + i];
        }
        #pragma unroll
        for (int off = 1; off < 64; off <<= 1) {
            s += __shfl_xor(s, off, 64);
            s2 += __shfl_xor(s2, off, 64);
        }
        if (lane == 0) {
            float mean = s * invN;
            float var = s2 * invN - mean * mean;
            float scale = g[o] / sqrtf(var + 1e-5f);
            float shift = bt[o] - mean * scale;
            ss[o * 2 + 0] = scale;
            ss[o * 2 + 1] = mode ? shift : shift / scale;
        }
    }
}

struct MMQ {
    const float* W;
    const unsigned short* Xp;
    const float* ssin;
    unsigned short* Yp;
    float* Ymax;
    float* pS;
    float* pS2;
    int cin;
    // fused last-block fin
    const float* gam;
    const float* bet;
    float* ssout;
    int* cnt;
    int total;   // blocks for this scale
    int gxF;     // partials per channel
    float invN;
    int finmode;
    int coutF;
};

struct GQ {
    const float* W;
    const unsigned short* Z;
    const int* idxb;
    const ushort4* relb;
    unsigned short* Xp;
    float* pS;
    float* pS2;
    const float* gam;
    const float* bet;
    float* ssout;
    int* cnt;
    int total;
    int gxF;
    float invN;
};

// ------------------------------------------------------------------
// prep: blocks [0,1024): transpose feats tile into LDS AND dense layer0
// feature GEMM for both scales straight from LDS.
// blocks [1024,2048): dual-radius ball query + center gather.
// Also zeroes the fin counters (block 1024).
__global__ __launch_bounds__(256) void k_prep(const float* __restrict__ xyz,
                                              const float* __restrict__ feats,
                                              const int* __restrict__ inds,
                                              const float* __restrict__ W0,
                                              const float* __restrict__ W1,
                                              unsigned short* __restrict__ Z0,
                                              unsigned short* __restrict__ Z1,
                                              float* __restrict__ out,
                                              int* __restrict__ idx0, ushort4* __restrict__ rel0,
                                              int* __restrict__ idx1, ushort4* __restrict__ rel1,
                                              int* __restrict__ cnts,
                                              float r0sq, float r1sq) {
    __shared__ __align__(16) unsigned short T[64][72];
    __shared__ __align__(16) unsigned short Wa2[2 * 2 * 4 * 64 * 8];
    int bx = blockIdx.x;
    const int tid = threadIdx.x;
    if (bx < 1024) {
        int b = bx >> 8;
        int n0 = (bx & 255) << 6;
        int tn = tid & 63;
        int c0 = tid >> 6;
        const float* fp = feats + (size_t)b * C_ * N_ + n0 + tn;
        #pragma unroll
        for (int it = 0; it < 16; ++it) {
            int c = it * 4 + c0;
            T[c][tn] = f2bf(fp[(size_t)c * N_]);
        }
        for (int s = tid; s < 2 * 2 * 4 * 64; s += 256) {
            int scale = s >> 9;
            int r = s & 511;
            int kb = r >> 8;
            int ot = (r >> 6) & 3;
            int sl = r & 63;
            int o = ot * 16 + (sl & 15);
            int cb = kb * 32 + (sl >> 4) * 8;
            const float* W = scale ? W1 : W0;
            unsigned int pk[4];
            #pragma unroll
            for (int e2 = 0; e2 < 4; ++e2)
                pk[e2] = (unsigned int)f2bf(W[(size_t)o * 67 + 3 + cb + e2 * 2]) |
                         ((unsigned int)f2bf(W[(size_t)o * 67 + 3 + cb + e2 * 2 + 1]) << 16);
            *(uint4*)&Wa2[(size_t)s * 8] = make_uint4(pk[0], pk[1], pk[2], pk[3]);
        }
        __syncthreads();

        const int lane = tid & 63;
        const int wid = tid >> 6;
        const int q = lane >> 4;
        const int jl = lane & 15;
        bf16x8 bfr[2];
        #pragma unroll
        for (int kb = 0; kb < 2; ++kb) {
            union { bf16x8 v; unsigned short u[8]; } tmp;
            #pragma unroll
            for (int e = 0; e < 8; ++e) tmp.u[e] = T[kb * 32 + q * 8 + e][wid * 16 + jl];
            bfr[kb] = tmp.v;
        }
        size_t n = (size_t)b * N_ + n0 + wid * 16 + jl;
        #pragma unroll
        for (int sc2 = 0; sc2 < 2; ++sc2) {
            unsigned short* Z = sc2 ? Z1 : Z0;
            f32x4 acc[4];
            #pragma unroll
            for (int ot = 0; ot < 4; ++ot) acc[ot] = (f32x4){0.f, 0.f, 0.f, 0.f};
            #pragma unroll
            for (int kb = 0; kb < 2; ++kb) {
                #pragma unroll
                for (int ot = 0; ot < 4; ++ot) {
                    bf16x8 a = *(const bf16x8*)&Wa2[(((sc2 * 2 + kb) * 4 + ot) * 64 + lane) * 8];
                    acc[ot] = __builtin_amdgcn_mfma_f32_16x16x32_bf16(a, bfr[kb], acc[ot], 0, 0, 0);
                }
            }
            #pragma unroll
            for (int ot = 0; ot < 4; ++ot)
                *(uint2*)&Z[n * 64 + ot * 16 + q * 4] =
                    make_uint2(cvt_pk(acc[ot][0], acc[ot][1]), cvt_pk(acc[ot][2], acc[ot][3]));
        }
        return;
    }
    if (bx == 1024 && tid < 8) cnts[tid] = 0;
    // ---- ball region ----
    int lane = tid & 63;
    int t = (bx - 1024) * 4 + (tid >> 6);
    int b = t >> 10;
    int n0 = inds[t];
    const float* bp = xyz + (size_t)b * N_ * 3;
    float qx = bp[n0 * 3 + 0], qy = bp[n0 * 3 + 1], qz = bp[n0 * 3 + 2];
    if (lane == 0) {
        out[t * 3 + 0] = qx;
        out[t * 3 + 1] = qy;
        out[t * 3 + 2] = qz;
        out[OUT_XYZ_ELEMS + OUT_FEAT_ELEMS + t] = (float)n0;
    }
    int cnt0 = 0, cnt1 = 0, first0 = n0, first1 = n0;
    ushort4 rf0 = make_ushort4(0, 0, 0, 0), rf1 = make_ushort4(0, 0, 0, 0);
    for (int base = 0; base < N_ && (cnt0 < 16 || cnt1 < 32); base += 64) {
        int n = base + lane;
        float dx = __fsub_rn(bp[n * 3 + 0], qx);
        float dy = __fsub_rn(bp[n * 3 + 1], qy);
        float dz = __fsub_rn(bp[n * 3 + 2], qz);
        float d2 = __fadd_rn(__fadd_rn(__fmul_rn(dx, dx), __fmul_rn(dy, dy)), __fmul_rn(dz, dz));
        unsigned long long m1 = __ballot(d2 < r1sq);
        unsigned long long m0 = __ballot(d2 < r0sq);
        if (cnt1 >= 32) m1 &= m0;
        while (m1) {
            int bit = (int)__builtin_ctzll(m1);
            m1 &= m1 - 1;
            int nn = base + bit;
            float sx = __shfl(dx, bit), sy = __shfl(dy, bit), sz = __shfl(dz, bit);
            ushort4 r = make_ushort4(f2bf(sx), f2bf(sy), f2bf(sz), 0);
            if (cnt1 < 32) {
                if (cnt1 == 0) { first1 = nn; rf1 = r; }
                if (lane == 0) { idx1[t * 32 + cnt1] = nn; rel1[t * 32 + cnt1] = r; }
                cnt1++;
                if (cnt1 == 32) m1 &= m0;
            }
            if (cnt0 < 16 && ((m0 >> bit) & 1ull)) {
                if (cnt0 == 0) { first0 = nn; rf0 = r; }
                if (lane == 0) { idx0[t * 16 + cnt0] = nn; rel0[t * 16 + cnt0] = r; }
                cnt0++;
            }
            if (cnt1 >= 32 && cnt0 >= 16) break;
        }
    }
    if (lane == 0) {
        for (int k2 = cnt0; k2 < 16; ++k2) { idx0[t * 16 + k2] = first0; rel0[t * 16 + k2] = rf0; }
        for (int k2 = cnt1; k2 < 32; ++k2) { idx1[t * 32 + k2] = first1; rel1[t * 32 + k2] = rf1; }
    }
}

// ------------------------------------------------------------------
// gather layer0: bufB[o][j] = Z[idx_j][o] + Wxyz[o]·rel_j, + BN stats
// (+ fused last-block fin).
template <int TPW, int NJL, int NSL, int JBL>
__device__ __forceinline__ void gath_body(const GQ P, int bx, float* sm1, float* sm2) {
    const int jx = ((bx & 7) << (JBL - 3)) | (bx >> 3);
    const int tid = threadIdx.x;
    const int lane = tid & 63;
    const int wid = tid >> 6;
    const int q = lane >> 4;
    const int jl = lane & 15;
    const int wtile0 = (jx * 4 + wid) * TPW;

    int nidxA[TPW];
    ushort4 rlA[TPW];
    #pragma unroll
    for (int i = 0; i < TPW; ++i) {
        int jj = (wtile0 + i) * 16 + jl;
        nidxA[i] = P.idxb[jj];
        rlA[i] = P.relb[jj];
    }

    float wx[2][8], wy[2][8], wz[2][8];
    #pragma unroll
    for (int kb = 0; kb < 2; ++kb)
        #pragma unroll
        for (int e = 0; e < 8; ++e) {
            int o = kb * 32 + q * 8 + e;
            wx[kb][e] = P.W[(size_t)o * 67 + 0];
            wy[kb][e] = P.W[(size_t)o * 67 + 1];
            wz[kb][e] = P.W[(size_t)o * 67 + 2];
        }

    bf16x8 zr[TPW][2];
    #pragma unroll
    for (int i = 0; i < TPW; ++i) {
        int jj = (wtile0 + i) * 16 + jl;
        int b = jj >> (NSL + 10);
        size_t nn = (size_t)b * N_ + nidxA[i];
        zr[i][0] = *(const bf16x8*)&P.Z[nn * 64 + q * 8];
        zr[i][1] = *(const bf16x8*)&P.Z[nn * 64 + 32 + q * 8];
    }

    float s1g[2][8], s2g[2][8];
    #pragma unroll
    for (int kb = 0; kb < 2; ++kb)
        #pragma unroll
        for (int e = 0; e < 8; ++e) { s1g[kb][e] = 0.f; s2g[kb][e] = 0.f; }

    #pragma unroll
    for (int i = 0; i < TPW; ++i) {
        int jj = (wtile0 + i) * 16 + jl;
        float rx = bf2f(rlA[i].x), ry = bf2f(rlA[i].y), rz = bf2f(rlA[i].z);
        #pragma unroll
        for (int kb = 0; kb < 2; ++kb) {
            unsigned int pk[4];
            #pragma unroll
            for (int e2 = 0; e2 < 4; ++e2) {
                float vv[2];
                #pragma unroll
                for (int h = 0; h < 2; ++h) {
                    int e = e2 * 2 + h;
                    float v = bf2f((unsigned short)zr[i][kb][e]);
                    v = fmaf(wx[kb][e], rx, v);
                    v = fmaf(wy[kb][e], ry, v);
                    v = fmaf(wz[kb][e], rz, v);
                    s1g[kb][e] += v;
                    s2g[kb][e] = fmaf(v, v, s2g[kb][e]);
                    vv[h] = v;
                }
                pk[e2] = cvt_pk(vv[0], vv[1]);
            }
            *(uint4*)&P.Xp[((size_t)(((kb * 4 + q) << NJL) + jj)) * 8] =
                make_uint4(pk[0], pk[1], pk[2], pk[3]);
        }
    }

    #pragma unroll
    for (int kb = 0; kb < 2; ++kb)
        #pragma unroll
        for (int e = 0; e < 8; ++e) {
            float v1 = s1g[kb][e], v2 = s2g[kb][e];
            v1 += __shfl_xor(v1, 1); v2 += __shfl_xor(v2, 1);
            v1 += __shfl_xor(v1, 2); v2 += __shfl_xor(v2, 2);
            v1 += __shfl_xor(v1, 4); v2 += __shfl_xor(v2, 4);
            v1 += __shfl_xor(v1, 8); v2 += __shfl_xor(v2, 8);
            s1g[kb][e] = v1; s2g[kb][e] = v2;
        }
    if (jl == 0) {
        #pragma unroll
        for (int kb = 0; kb < 2; ++kb)
            #pragma unroll
            for (int e = 0; e < 8; ++e) {
                int o = kb * 32 + q * 8 + e;
                sm1[wid * 64 + o] = s1g[kb][e];
                sm2[wid * 64 + o] = s2g[kb][e];
            }
    }
    __syncthreads();
    for (int o = tid; o < 64; o += 256) {
        P.pS[(size_t)o * PST + jx] = sm1[o] + sm1[64 + o] + sm1[128 + o] + sm1[192 + o];
        P.pS2[(size_t)o * PST + jx] = sm2[o] + sm2[64 + o] + sm2[128 + o] + sm2[192 + o];
    }

    // fused last-block fin
    __shared__ int isLast;
    __threadfence();
    if (tid == 0) isLast = (atomicAdd(P.cnt, 1) == P.total - 1) ? 1 : 0;
    __syncthreads();
    if (isLast) {
        __threadfence();
        fin_block(P.pS, P.pS2, P.gam, P.bet, P.ssout, 64, P.gxF, P.invN, 0);
        if (tid == 0) *P.cnt = 0;
    }
}

__global__ __launch_bounds__(256) void k_gath2(GQ p0, GQ p1, int split) {
    __shared__ float sm1[4 * 64], sm2[4 * 64];
    if ((int)blockIdx.x < split) gath_body<2, 16, 4, 9>(p0, blockIdx.x, sm1, sm2);
    else gath_body<2, 17, 5, 10>(p1, blockIdx.x - split, sm1, sm2);
}

// ------------------------------------------------------------------
// layer-1 streaming MFMA GEMM body (NPH phases x 64 j, double-buffered
// global_load_lds staging, BN folded, fused last-block fin).
template <int KB, int OT, int NPH, int NJL, int JXL>
__device__ __forceinline__ void mm_body(const MMQ P, int bx,
                                        unsigned short* Wa, unsigned short* XL,
                                        float* sm1, float* sm2) {
    constexpr int KB4 = KB * 4;
    const int oy = bx >> JXL;
    const int jxr = bx & ((1 << JXL) - 1);
    const int jx = ((jxr & 7) << (JXL - 3)) | (jxr >> 3);
    const int tid = threadIdx.x;
    const int lane = tid & 63;
    const int wid = tid >> 6;
    const int q = lane >> 4;
    const int jl = lane & 15;
    const int oybase = oy * OT * 16;
    const int jbase = jx * (NPH * 64);

    auto STAGE = [&](int buf, int p) {
        #pragma unroll
        for (int c2 = 0; c2 < KB; ++c2) {
            int chunk = wid * KB + c2;
            const unsigned short* gsrc =
                P.Xp + ((size_t)((chunk << NJL) + jbase + p * 64 + lane)) * 8;
            unsigned short* ldst = XL + ((size_t)(buf * KB4 + chunk) * 64) * 8;
            __builtin_amdgcn_global_load_lds((gk_gvoid*)gsrc, (gk_svoid*)ldst, 16, 0, 0);
        }
    };

    STAGE(0, 0);

    for (int s = tid; s < KB * OT * 64; s += 256) {
        int kb = s / (OT * 64);
        int r = s - kb * (OT * 64);
        int ot = r >> 6;
        int sl = r & 63;
        int o = oybase + ot * 16 + (sl & 15);
        int cbase = kb * 32 + (sl >> 4) * 8;
        unsigned int pk[4];
        #pragma unroll
        for (int e2 = 0; e2 < 4; ++e2) {
            int c0 = cbase + e2 * 2, c1 = c0 + 1;
            float w0 = (c0 < P.cin) ? P.W[(size_t)o * P.cin + c0] * P.ssin[c0 * 2 + 0] : 0.f;
            float w1 = (c1 < P.cin) ? P.W[(size_t)o * P.cin + c1] * P.ssin[c1 * 2 + 0] : 0.f;
            pk[e2] = (unsigned int)f2bf(w0) | ((unsigned int)f2bf(w1) << 16);
        }
        *(uint4*)&Wa[(size_t)s * 8] = make_uint4(pk[0], pk[1], pk[2], pk[3]);
    }
    __syncthreads();

    bf16x8 a[KB][OT];
    #pragma unroll
    for (int kb = 0; kb < KB; ++kb)
        #pragma unroll
        for (int ot = 0; ot < OT; ++ot)
            a[kb][ot] = *(const bf16x8*)&Wa[((kb * OT + ot) * 64 + lane) * 8];

    float tt[KB][8];
    #pragma unroll
    for (int kb = 0; kb < KB; ++kb)
        #pragma unroll
        for (int e = 0; e < 8; ++e) {
            int c = kb * 32 + q * 8 + e;
            tt[kb][e] = (c < P.cin) ? P.ssin[c * 2 + 1] : 0.f;
        }

    float s1_[OT][4], s2_[OT][4];
    #pragma unroll
    for (int ot = 0; ot < OT; ++ot)
        #pragma unroll
        for (int r = 0; r < 4; ++r) { s1_[ot][r] = 0.f; s2_[ot][r] = 0.f; }

    #pragma unroll
    for (int p = 0; p < NPH; ++p) {
        if (p + 1 < NPH) STAGE((p + 1) & 1, p + 1);
        const int buf = p & 1;
        const int jj = jbase + p * 64 + wid * 16 + jl;

        f32x4 acc[OT];
        #pragma unroll
        for (int ot = 0; ot < OT; ++ot) acc[ot] = (f32x4){0.f, 0.f, 0.f, 0.f};

        #pragma unroll
        for (int kb = 0; kb < KB; ++kb) {
            bf16x8 bf = *(const bf16x8*)&XL[((size_t)(buf * KB4 + kb * 4 + q) * 64 + wid * 16 + jl) * 8];
            union { bf16x8 v; unsigned int u[4]; } in, outp;
            in.v = bf;
            #pragma unroll
            for (int wd = 0; wd < 4; ++wd) {
                float lo = __uint_as_float(in.u[wd] << 16);
                float hi = __uint_as_float(in.u[wd] & 0xffff0000u);
                lo = fmaxf(lo + tt[kb][2 * wd], 0.f);
                hi = fmaxf(hi + tt[kb][2 * wd + 1], 0.f);
                outp.u[wd] = cvt_pk(lo, hi);
            }
            bf = outp.v;
            #pragma unroll
            for (int ot = 0; ot < OT; ++ot)
                acc[ot] = __builtin_amdgcn_mfma_f32_16x16x32_bf16(a[kb][ot], bf, acc[ot], 0, 0, 0);
        }

        #pragma unroll
        for (int ot = 0; ot < OT; ++ot)
            #pragma unroll
            for (int r = 0; r < 4; ++r) {
                float v = acc[ot][r];
                s1_[ot][r] += v;
                s2_[ot][r] = fmaf(v, v, s2_[ot][r]);
            }

        #pragma unroll
        for (int ot = 0; ot < OT; ++ot) {
            int o0 = oybase + ot * 16 + q * 4;
            *(uint2*)&P.Yp[((size_t)(((o0 >> 3) << NJL) + jj)) * 8 + (o0 & 7)] =
                make_uint2(cvt_pk(acc[ot][0], acc[ot][1]), cvt_pk(acc[ot][2], acc[ot][3]));
        }
        __syncthreads();
    }

    #pragma unroll
    for (int ot = 0; ot < OT; ++ot)
        #pragma unroll
        for (int r = 0; r < 4; ++r) {
            float v1 = s1_[ot][r], v2 = s2_[ot][r];
            v1 += __shfl_xor(v1, 1); v2 += __shfl_xor(v2, 1);
            v1 += __shfl_xor(v1, 2); v2 += __shfl_xor(v2, 2);
            v1 += __shfl_xor(v1, 4); v2 += __shfl_xor(v2, 4);
            v1 += __shfl_xor(v1, 8); v2 += __shfl_xor(v2, 8);
            s1_[ot][r] = v1; s2_[ot][r] = v2;
        }
    if (jl == 0) {
        #pragma unroll
        for (int ot = 0; ot < OT; ++ot)
            #pragma unroll
            for (int r = 0; r < 4; ++r) {
                sm1[wid * (OT * 16) + ot * 16 + q * 4 + r] = s1_[ot][r];
                sm2[wid * (OT * 16) + ot * 16 + q * 4 + r] = s2_[ot][r];
            }
    }
    __syncthreads();
    for (int o = tid; o < OT * 16; o += 256) {
        float a1 = sm1[o] + sm1[OT * 16 + o] + sm1[2 * OT * 16 + o] + sm1[3 * OT * 16 + o];
        float a2 = sm2[o] + sm2[OT * 16 + o] + sm2[2 * OT * 16 + o] + sm2[3 * OT * 16 + o];
        P.pS[(size_t)(oybase + o) * PST + jx] = a1;
        P.pS2[(size_t)(oybase + o) * PST + jx] = a2;
    }

    __shared__ int isLast;
    __threadfence();
    if (tid == 0) isLast = (atomicAdd(P.cnt, 1) == P.total - 1) ? 1 : 0;
    __syncthreads();
    if (isLast) {
        __threadfence();
        fin_block(P.pS, P.pS2, P.gam, P.bet, P.ssout, P.coutF, P.gxF, P.invN, P.finmode);
        if (tid == 0) *P.cnt = 0;
    }
}

template <int KB0, int OT0, int NJL0, int JXL0,
          int KB1, int OT1, int NJL1, int JXL1, int NPH>
__global__ __launch_bounds__(256) void k_mm2(MMQ p0, MMQ p1, int split) {
    constexpr int WAMAX = ((KB0 * OT0 > KB1 * OT1) ? KB0 * OT0 : KB1 * OT1) * 512;
    constexpr int KBMAX = (KB0 > KB1) ? KB0 : KB1;
    constexpr int XLSZ = 2 * KBMAX * 4 * 64 * 8;
    constexpr int OTMAX = (OT0 > OT1) ? OT0 : OT1;
    __shared__ __align__(16) unsigned short Wa[WAMAX];
    __shared__ __align__(16) unsigned short XL[XLSZ];
    __shared__ float sm1[4 * OTMAX * 16], sm2[4 * OTMAX * 16];
    if ((int)blockIdx.x < split)
        mm_body<KB0, OT0, NPH, NJL0, JXL0>(p0, blockIdx.x, Wa, XL, sm1, sm2);
    else
        mm_body<KB1, OT1, NPH, NJL1, JXL1>(p1, blockIdx.x - split, Wa, XL, sm1, sm2);
}

// ------------------------------------------------------------------
// layer-2 POOL GEMM, SWAPPED MFMA OPERANDS (lane holds 4 j of one o);
// pool = 3 fmax + 2 shfl.  Phase = 128 j; fused last-block fin (mode 1).
template <int KB, int OT, int NPH, int NSPOOL, int NJL, int JXL>
__device__ __forceinline__ void mmp_body(const MMQ P, int bx,
                                         unsigned short* Wa, unsigned short* XL,
                                         float* sm1, float* sm2) {
    constexpr int KB4 = KB * 4;
    const int oy = bx >> JXL;
    const int jxr = bx & ((1 << JXL) - 1);
    const int jx = ((jxr & 7) << (JXL - 3)) | (jxr >> 3);
    const int tid = threadIdx.x;
    const int lane = tid & 63;
    const int wid = tid >> 6;
    const int q = lane >> 4;
    const int jl = lane & 15;
    const int oybase = oy * OT * 16;
    const int jbase = jx * (NPH * 128);

    auto STAGE = [&](int buf, int p) {
        #pragma unroll
        for (int s0 = 0; s0 < 2 * KB; ++s0) {
            int s = wid + 4 * s0;
            int chunk = s >> 1;
            int half = s & 1;
            const unsigned short* gsrc =
                P.Xp + ((size_t)((chunk << NJL) + jbase + p * 128 + half * 64 + lane)) * 8;
            unsigned short* ldst = XL + ((size_t)((buf * KB4 + chunk) * 128 + half * 64)) * 8;
            __builtin_amdgcn_global_load_lds((gk_gvoid*)gsrc, (gk_svoid*)ldst, 16, 0, 0);
        }
    };

    STAGE(0, 0);

    for (int s = tid; s < KB * OT * 64; s += 256) {
        int kb = s / (OT * 64);
        int r = s - kb * (OT * 64);
        int ot = r >> 6;
        int sl = r & 63;
        int o = oybase + ot * 16 + (sl & 15);
        int cbase = kb * 32 + (sl >> 4) * 8;
        unsigned int pk[4];
        #pragma unroll
        for (int e2 = 0; e2 < 4; ++e2) {
            int c0 = cbase + e2 * 2, c1 = c0 + 1;
            float w0 = (c0 < P.cin) ? P.W[(size_t)o * P.cin + c0] * P.ssin[c0 * 2 + 0] : 0.f;
            float w1 = (c1 < P.cin) ? P.W[(size_t)o * P.cin + c1] * P.ssin[c1 * 2 + 0] : 0.f;
            pk[e2] = (unsigned int)f2bf(w0) | ((unsigned int)f2bf(w1) << 16);
        }
        *(uint4*)&Wa[(size_t)s * 8] = make_uint4(pk[0], pk[1], pk[2], pk[3]);
    }
    __syncthreads();

    bf16x8 a[KB][OT];
    #pragma unroll
    for (int kb = 0; kb < KB; ++kb)
        #pragma unroll
        for (int ot = 0; ot < OT; ++ot)
            a[kb][ot] = *(const bf16x8*)&Wa[((kb * OT + ot) * 64 + lane) * 8];

    float tt[KB][8];
    #pragma unroll
    for (int kb = 0; kb < KB; ++kb)
        #pragma unroll
        for (int e = 0; e < 8; ++e) {
            int c = kb * 32 + q * 8 + e;
            tt[kb][e] = (c < P.cin) ? P.ssin[c * 2 + 1] : 0.f;
        }

    float s1_[OT][4], s2_[OT][4];
    #pragma unroll
    for (int ot = 0; ot < OT; ++ot)
        #pragma unroll
        for (int r = 0; r < 4; ++r) { s1_[ot][r] = 0.f; s2_[ot][r] = 0.f; }

    #pragma unroll
    for (int p = 0; p < NPH; ++p) {
        if (p + 1 < NPH) STAGE((p + 1) & 1, p + 1);
        const int buf = p & 1;
        float pm[2][OT];

        #pragma unroll
        for (int t2 = 0; t2 < 2; ++t2) {
            f32x4 acc[OT];
            #pragma unroll
            for (int ot = 0; ot < OT; ++ot) acc[ot] = (f32x4){0.f, 0.f, 0.f, 0.f};

            #pragma unroll
            for (int kb = 0; kb < KB; ++kb) {
                bf16x8 bf = *(const bf16x8*)&XL[((size_t)((buf * KB4 + kb * 4 + q) * 128 +
                                                          wid * 32 + t2 * 16 + jl)) * 8];
                union { bf16x8 v; unsigned int u[4]; } in, outp;
                in.v = bf;
                #pragma unroll
                for (int wd = 0; wd < 4; ++wd) {
                    float lo = __uint_as_float(in.u[wd] << 16);
                    float hi = __uint_as_float(in.u[wd] & 0xffff0000u);
                    lo = fmaxf(lo + tt[kb][2 * wd], 0.f);
                    hi = fmaxf(hi + tt[kb][2 * wd + 1], 0.f);
                    outp.u[wd] = cvt_pk(lo, hi);
                }
                bf = outp.v;
                #pragma unroll
                for (int ot = 0; ot < OT; ++ot)
                    acc[ot] = __builtin_amdgcn_mfma_f32_16x16x32_bf16(bf, a[kb][ot], acc[ot], 0, 0, 0);
            }

            #pragma unroll
            for (int ot = 0; ot < OT; ++ot) {
                float mx = fmaxf(fmaxf(acc[ot][0], acc[ot][1]), fmaxf(acc[ot][2], acc[ot][3]));
                #pragma unroll
                for (int r = 0; r < 4; ++r) {
                    float v = acc[ot][r];
                    s1_[ot][r] += v;
                    s2_[ot][r] = fmaf(v, v, s2_[ot][r]);
                }
                mx = fmaxf(mx, __shfl_xor(mx, 16));
                mx = fmaxf(mx, __shfl_xor(mx, 32));
                pm[t2][ot] = mx;
            }
        }

        int j0 = jbase + p * 128 + wid * 32;
        if (NSPOOL == 32) {
            if (lane < 16) {
                int bm = j0 >> 5;
                #pragma unroll
                for (int ot = 0; ot < OT; ++ot)
                    P.Ymax[(size_t)bm * 128 + oybase + ot * 16 + jl] = fmaxf(pm[0][ot], pm[1][ot]);
            }
        } else {
            if (lane < 16) {
                int bm0 = j0 >> 4;
                #pragma unroll
                for (int t2 = 0; t2 < 2; ++t2)
                    #pragma unroll
                    for (int ot = 0; ot < OT; ++ot)
                        P.Ymax[(size_t)(bm0 + t2) * 128 + oybase + ot * 16 + jl] = pm[t2][ot];
            }
        }
        __syncthreads();
    }

    #pragma unroll
    for (int ot = 0; ot < OT; ++ot) {
        float v1 = s1_[ot][0] + s1_[ot][1] + s1_[ot][2] + s1_[ot][3];
        float v2 = s2_[ot][0] + s2_[ot][1] + s2_[ot][2] + s2_[ot][3];
        v1 += __shfl_xor(v1, 16); v2 += __shfl_xor(v2, 16);
        v1 += __shfl_xor(v1, 32); v2 += __shfl_xor(v2, 32);
        if (lane < 16) {
            sm1[wid * (OT * 16) + ot * 16 + jl] = v1;
            sm2[wid * (OT * 16) + ot * 16 + jl] = v2;
        }
    }
    __syncthreads();
    for (int o = tid; o < OT * 16; o += 256) {
        float a1 = sm1[o] + sm1[OT * 16 + o] + sm1[2 * OT * 16 + o] + sm1[3 * OT * 16 + o];
        float a2 = sm2[o] + sm2[OT * 16 + o] + sm2[2 * OT * 16 + o] + sm2[3 * OT * 16 + o];
        P.pS[(size_t)(oybase + o) * PST + jx] = a1;
        P.pS2[(size_t)(oybase + o) * PST + jx] = a2;
    }

    __shared__ int isLast;
    __threadfence();
    if (tid == 0) isLast = (atomicAdd(P.cnt, 1) == P.total - 1) ? 1 : 0;
    __syncthreads();
    if (isLast) {
        __threadfence();
        fin_block(P.pS, P.pS2, P.gam, P.bet, P.ssout, P.coutF, P.gxF, P.invN, P.finmode);
        if (tid == 0) *P.cnt = 0;
    }
}

template <int KB0, int OT0, int NJL0, int NSP0, int JXL0,
          int KB1, int OT1, int NJL1, int NSP1, int JXL1, int NPH>
__global__ __launch_bounds__(256) void k_mmp(MMQ p0, MMQ p1, int split) {
    constexpr int WAMAX = ((KB0 * OT0 > KB1 * OT1) ? KB0 * OT0 : KB1 * OT1) * 512;
    constexpr int KBMAX = (KB0 > KB1) ? KB0 : KB1;
    constexpr int XLSZ = 2 * KBMAX * 4 * 128 * 8;
    constexpr int OTMAX = (OT0 > OT1) ? OT0 : OT1;
    __shared__ __align__(16) unsigned short Wa[WAMAX];
    __shared__ __align__(16) unsigned short XL[XLSZ];
    __shared__ float sm1[4 * OTMAX * 16], sm2[4 * OTMAX * 16];
    if ((int)blockIdx.x < split)
        mmp_body<KB0, OT0, NPH, NSP0, NJL0, JXL0>(p0, blockIdx.x, Wa, XL, sm1, sm2);
    else
        mmp_body<KB1, OT1, NPH, NSP1, NJL1, JXL1>(p1, blockIdx.x - split, Wa, XL, sm1, sm2);
}

// ------------------------------------------------------------------
__global__ __launch_bounds__(256) void k_poolfin2(const float* __restrict__ Ymax0, const float* __restrict__ ss0,
                                                  const float* __restrict__ Ymax1, const float* __restrict__ ss1,
                                                  float* __restrict__ out) {
    __shared__ float T[128][65];
    int blk = blockIdx.x;
    const float* Ymax;
    const float* ss;
    int o_off;
    if (blk < 64) { Ymax = Ymax0; ss = ss0; o_off = 0; }
    else { blk -= 64; Ymax = Ymax1; ss = ss1; o_off = 128; }
    int b = blk >> 4, mc = blk & 15;
    int bm0 = b * M_ + mc * 64;
    for (int s = threadIdx.x; s < 64 * 32; s += 256) {
        int row = s >> 5;
        int c4 = s & 31;
        float4 v = *(const float4*)&Ymax[(size_t)(bm0 + row) * 128 + c4 * 4];
        T[c4 * 4 + 0][row] = v.x;
        T[c4 * 4 + 1][row] = v.y;
        T[c4 * 4 + 2][row] = v.z;
        T[c4 * 4 + 3][row] = v.w;
    }
    __syncthreads();
    for (int s = threadIdx.x; s < 128 * 16; s += 256) {
        int o = s >> 4, m4 = s & 15;
        float scv = ss[o * 2 + 0], shv = ss[o * 2 + 1];
        float4 v = make_float4(T[o][m4 * 4], T[o][m4 * 4 + 1], T[o][m4 * 4 + 2], T[o][m4 * 4 + 3]);
        v.x = fmaxf(fmaf(v.x, scv, shv), 0.f);
        v.y = fmaxf(fmaf(v.y, scv, shv), 0.f);
        v.z = fmaxf(fmaf(v.z, scv, shv), 0.f);
        v.w = fmaxf(fmaf(v.w, scv, shv), 0.f);
        *(float4*)&out[OUT_XYZ_ELEMS + ((size_t)(b * 256 + o_off + o)) * M_ + mc * 64 + m4 * 4] = v;
    }
}

// ------------------------------------------------------------------
extern "C" void kernel_launch(void* const* d_in, const int* in_sizes, int n_in,
                              void* d_out, int out_size, void* d_ws, size_t ws_size,
                              hipStream_t stream) {
    const float* xyz = (const float*)d_in[0];
    const float* feats = (const float*)d_in[1];
    const int* inds = (const int*)d_in[2];
    const float* w[2][3];
    const float* gg[2][3];
    const float* bb[2][3];
    int k = 3;
    for (int i = 0; i < 2; ++i)
        for (int l = 0; l < 3; ++l) {
            w[i][l] = (const float*)d_in[k++];
            gg[i][l] = (const float*)d_in[k++];
            bb[i][l] = (const float*)d_in[k++];
        }
    float* out = (float*)d_out;

    const int Nj0 = B_ * M_ * 16;  // 65536 = 1<<16
    const int Nj1 = B_ * M_ * 32;  // 131072 = 1<<17

    unsigned short* Z0 = (unsigned short*)d_ws;
    unsigned short* Z1 = Z0 + (size_t)B_ * N_ * 64;
    unsigned short* bufB0 = Z1 + (size_t)B_ * N_ * 64;
    unsigned short* bufA0 = bufB0 + (size_t)8 * Nj0 * 8;
    unsigned short* bufB1 = bufA0 + (size_t)12 * Nj0 * 8;
    unsigned short* bufA1 = bufB1 + (size_t)8 * Nj1 * 8;
    float* Ymax0 = (float*)(bufA1 + (size_t)12 * Nj1 * 8);
    float* Ymax1 = Ymax0 + (size_t)B_ * M_ * 128;
    float* pS0 = Ymax1 + (size_t)B_ * M_ * 128;
    float* pS2_0 = pS0 + (size_t)128 * PST;
    float* pS1 = pS2_0 + (size_t)128 * PST;
    float* pS2_1 = pS1 + (size_t)128 * PST;
    float* ss0 = pS2_1 + (size_t)128 * PST;
    float* ss1 = ss0 + 256;
    int* idx0 = (int*)(ss1 + 256);
    int* idx1 = idx0 + Nj0;
    ushort4* rel0 = (ushort4*)(idx1 + Nj1);
    ushort4* rel1 = rel0 + Nj0;
    int* cnts = (int*)(rel1 + Nj1);   // 8 counters

    const float inv0 = 1.f / Nj0, inv1 = 1.f / Nj1;

    // 1) prep: transpose+dense-L0 (blocks 0-1023), ball (1024-2047), cnt zero
    k_prep<<<2048, 256, 0, stream>>>(xyz, feats, inds, w[0][0], w[1][0], Z0, Z1, out,
                                     idx0, rel0, idx1, rel1, cnts,
                                     (float)(0.4 * 0.4), (float)(0.8 * 0.8));

    // 2) gather + xyz-add + stats (+fused fin) -> bufB, ss
    GQ g0{}, g1{};
    g0.W = w[0][0]; g0.Z = Z0; g0.idxb = idx0; g0.relb = rel0;
    g0.Xp = bufB0; g0.pS = pS0; g0.pS2 = pS2_0;
    g0.gam = gg[0][0]; g0.bet = bb[0][0]; g0.ssout = ss0;
    g0.cnt = cnts + 0; g0.total = 512; g0.gxF = 512; g0.invN = inv0;
    g1.W = w[1][0]; g1.Z = Z1; g1.idxb = idx1; g1.relb = rel1;
    g1.Xp = bufB1; g1.pS = pS1; g1.pS2 = pS2_1;
    g1.gam = gg[1][0]; g1.bet = bb[1][0]; g1.ssout = ss1;
    g1.cnt = cnts + 1; g1.total = 1024; g1.gxF = 1024; g1.invN = inv1;
    k_gath2<<<1536, 256, 0, stream>>>(g0, g1, 512);

    // 3) layer1 (+fused fin): NPH=4.  s0: KB2 OT4 (256 jx); s1: KB2 OT6 (512 jx).
    MMQ b0{}, b1{};
    b0.W = w[0][1]; b0.Xp = bufB0; b0.ssin = ss0; b0.Yp = bufA0;
    b0.pS = pS0; b0.pS2 = pS2_0; b0.cin = 64;
    b0.gam = gg[0][1]; b0.bet = bb[0][1]; b0.ssout = ss0;
    b0.cnt = cnts + 2; b0.total = 256; b0.gxF = 256; b0.invN = inv0; b0.finmode = 0; b0.coutF = 64;
    b1.W = w[1][1]; b1.Xp = bufB1; b1.ssin = ss1; b1.Yp = bufA1;
    b1.pS = pS1; b1.pS2 = pS2_1; b1.cin = 64;
    b1.gam = gg[1][1]; b1.bet = bb[1][1]; b1.ssout = ss1;
    b1.cnt = cnts + 3; b1.total = 512; b1.gxF = 512; b1.invN = inv1; b1.finmode = 0; b1.coutF = 96;
    k_mm2<2, 4, 16, 8,  2, 6, 17, 9,  4>
        <<<768, 256, 0, stream>>>(b0, b1, 256);

    // 4) layer2 POOL (swapped-operand, +fused fin mode1): NPH=4, s1 first.
    MMQ c0{}, c1{};
    c0.W = w[0][2]; c0.Xp = bufA0; c0.ssin = ss0; c0.Ymax = Ymax0;
    c0.pS = pS0; c0.pS2 = pS2_0; c0.cin = 64;
    c0.gam = gg[0][2]; c0.bet = bb[0][2]; c0.ssout = ss0;
    c0.cnt = cnts + 4; c0.total = 256; c0.gxF = 128; c0.invN = inv0; c0.finmode = 1; c0.coutF = 128;
    c1.W = w[1][2]; c1.Xp = bufA1; c1.ssin = ss1; c1.Ymax = Ymax1;
    c1.pS = pS1; c1.pS2 = pS2_1; c1.cin = 96;
    c1.gam = gg[1][2]; c1.bet = bb[1][2]; c1.ssout = ss1;
    c1.cnt = cnts + 5; c1.total = 512; c1.gxF = 256; c1.invN = inv1; c1.finmode = 1; c1.coutF = 128;
    k_mmp<3, 4, 17, 32, 8,  2, 4, 16, 16, 7,  4>
        <<<768, 256, 0, stream>>>(c1, c0, 512);

    // 5) final BN+ReLU + transpose
    k_poolfin2<<<128, 256, 0, stream>>>(Ymax0, ss0, Ymax1, ss1, out);
}

// Round 17
// 120.225 us; speedup vs baseline: 5.5798x; 5.5798x over previous
//
#include <hip/hip_runtime.h>
#include <math.h>

#define B_ 4
#define N_ 16384
#define M_ 1024
#define C_ 64

// output layout (floats): new_xyz [B*M*3] | feats [B*256*M] | inds [B*M]
#define OUT_XYZ_ELEMS (B_ * M_ * 3)
#define OUT_FEAT_ELEMS (B_ * 256 * M_)
#define PST 1024  // partial-stats stride (>= max j-blocks)

typedef __attribute__((ext_vector_type(8))) short bf16x8;
typedef __attribute__((ext_vector_type(4))) float f32x4;
typedef __attribute__((address_space(1))) const void gk_gvoid;
typedef __attribute__((address_space(3))) void gk_svoid;

__device__ __forceinline__ unsigned short f2bf(float f) {
    unsigned int u = __float_as_uint(f);
    u += 0x7fffu + ((u >> 16) & 1u);
    return (unsigned short)(u >> 16);
}
__device__ __forceinline__ float bf2f(unsigned short h) {
    return __uint_as_float(((unsigned int)h) << 16);
}
// hardware packed f32x2 -> bf16x2 (RNE), src0 -> low half
__device__ __forceinline__ unsigned int cvt_pk(float lo, float hi) {
    unsigned int r;
    asm("v_cvt_pk_bf16_f32 %0, %1, %2" : "=v"(r) : "v"(lo), "v"(hi));
    return r;
}

struct MMQ {
    const float* W;
    const unsigned short* Xp;
    const float* ssin;
    unsigned short* Yp;
    float* Ymax;
    float* pS;
    float* pS2;
    int cin;
};

struct GQ {
    const float* W;
    const unsigned short* Z;
    const int* idxb;
    const ushort4* relb;
    unsigned short* Xp;
    float* pS;
    float* pS2;
};

// ------------------------------------------------------------------
// prep: blocks [0,1024): transpose feats tile into LDS AND compute the
// dense layer0 feature GEMM for both scales straight from LDS.
// blocks [1024,2048): dual-radius ball query + center gather.
__global__ __launch_bounds__(256) void k_prep(const float* __restrict__ xyz,
                                              const float* __restrict__ feats,
                                              const int* __restrict__ inds,
                                              const float* __restrict__ W0,
                                              const float* __restrict__ W1,
                                              unsigned short* __restrict__ Z0,
                                              unsigned short* __restrict__ Z1,
                                              float* __restrict__ out,
                                              int* __restrict__ idx0, ushort4* __restrict__ rel0,
                                              int* __restrict__ idx1, ushort4* __restrict__ rel1,
                                              float r0sq, float r1sq) {
    __shared__ __align__(16) unsigned short T[64][72];
    __shared__ __align__(16) unsigned short Wa2[2 * 2 * 4 * 64 * 8];
    int bx = blockIdx.x;
    const int tid = threadIdx.x;
    if (bx < 1024) {
        int b = bx >> 8;
        int n0 = (bx & 255) << 6;
        int tn = tid & 63;
        int c0 = tid >> 6;
        const float* fp = feats + (size_t)b * C_ * N_ + n0 + tn;
        #pragma unroll
        for (int it = 0; it < 16; ++it) {
            int c = it * 4 + c0;
            T[c][tn] = f2bf(fp[(size_t)c * N_]);
        }
        for (int s = tid; s < 2 * 2 * 4 * 64; s += 256) {
            int scale = s >> 9;
            int r = s & 511;
            int kb = r >> 8;
            int ot = (r >> 6) & 3;
            int sl = r & 63;
            int o = ot * 16 + (sl & 15);
            int cb = kb * 32 + (sl >> 4) * 8;
            const float* W = scale ? W1 : W0;
            unsigned int pk[4];
            #pragma unroll
            for (int e2 = 0; e2 < 4; ++e2)
                pk[e2] = (unsigned int)f2bf(W[(size_t)o * 67 + 3 + cb + e2 * 2]) |
                         ((unsigned int)f2bf(W[(size_t)o * 67 + 3 + cb + e2 * 2 + 1]) << 16);
            *(uint4*)&Wa2[(size_t)s * 8] = make_uint4(pk[0], pk[1], pk[2], pk[3]);
        }
        __syncthreads();

        const int lane = tid & 63;
        const int wid = tid >> 6;
        const int q = lane >> 4;
        const int jl = lane & 15;
        bf16x8 bfr[2];
        #pragma unroll
        for (int kb = 0; kb < 2; ++kb) {
            union { bf16x8 v; unsigned short u[8]; } tmp;
            #pragma unroll
            for (int e = 0; e < 8; ++e) tmp.u[e] = T[kb * 32 + q * 8 + e][wid * 16 + jl];
            bfr[kb] = tmp.v;
        }
        size_t n = (size_t)b * N_ + n0 + wid * 16 + jl;
        #pragma unroll
        for (int sc2 = 0; sc2 < 2; ++sc2) {
            unsigned short* Z = sc2 ? Z1 : Z0;
            f32x4 acc[4];
            #pragma unroll
            for (int ot = 0; ot < 4; ++ot) acc[ot] = (f32x4){0.f, 0.f, 0.f, 0.f};
            #pragma unroll
            for (int kb = 0; kb < 2; ++kb) {
                #pragma unroll
                for (int ot = 0; ot < 4; ++ot) {
                    bf16x8 a = *(const bf16x8*)&Wa2[(((sc2 * 2 + kb) * 4 + ot) * 64 + lane) * 8];
                    acc[ot] = __builtin_amdgcn_mfma_f32_16x16x32_bf16(a, bfr[kb], acc[ot], 0, 0, 0);
                }
            }
            #pragma unroll
            for (int ot = 0; ot < 4; ++ot)
                *(uint2*)&Z[n * 64 + ot * 16 + q * 4] =
                    make_uint2(cvt_pk(acc[ot][0], acc[ot][1]), cvt_pk(acc[ot][2], acc[ot][3]));
        }
        return;
    }
    // ---- ball region ----
    int lane = tid & 63;
    int t = (bx - 1024) * 4 + (tid >> 6);
    int b = t >> 10;
    int n0 = inds[t];
    const float* bp = xyz + (size_t)b * N_ * 3;
    float qx = bp[n0 * 3 + 0], qy = bp[n0 * 3 + 1], qz = bp[n0 * 3 + 2];
    if (lane == 0) {
        out[t * 3 + 0] = qx;
        out[t * 3 + 1] = qy;
        out[t * 3 + 2] = qz;
        out[OUT_XYZ_ELEMS + OUT_FEAT_ELEMS + t] = (float)n0;
    }
    int cnt0 = 0, cnt1 = 0, first0 = n0, first1 = n0;
    ushort4 rf0 = make_ushort4(0, 0, 0, 0), rf1 = make_ushort4(0, 0, 0, 0);
    for (int base = 0; base < N_ && (cnt0 < 16 || cnt1 < 32); base += 64) {
        int n = base + lane;
        float dx = __fsub_rn(bp[n * 3 + 0], qx);
        float dy = __fsub_rn(bp[n * 3 + 1], qy);
        float dz = __fsub_rn(bp[n * 3 + 2], qz);
        float d2 = __fadd_rn(__fadd_rn(__fmul_rn(dx, dx), __fmul_rn(dy, dy)), __fmul_rn(dz, dz));
        unsigned long long m1 = __ballot(d2 < r1sq);
        unsigned long long m0 = __ballot(d2 < r0sq);
        if (cnt1 >= 32) m1 &= m0;
        while (m1) {
            int bit = (int)__builtin_ctzll(m1);
            m1 &= m1 - 1;
            int nn = base + bit;
            float sx = __shfl(dx, bit), sy = __shfl(dy, bit), sz = __shfl(dz, bit);
            ushort4 r = make_ushort4(f2bf(sx), f2bf(sy), f2bf(sz), 0);
            if (cnt1 < 32) {
                if (cnt1 == 0) { first1 = nn; rf1 = r; }
                if (lane == 0) { idx1[t * 32 + cnt1] = nn; rel1[t * 32 + cnt1] = r; }
                cnt1++;
                if (cnt1 == 32) m1 &= m0;
            }
            if (cnt0 < 16 && ((m0 >> bit) & 1ull)) {
                if (cnt0 == 0) { first0 = nn; rf0 = r; }
                if (lane == 0) { idx0[t * 16 + cnt0] = nn; rel0[t * 16 + cnt0] = r; }
                cnt0++;
            }
            if (cnt1 >= 32 && cnt0 >= 16) break;
        }
    }
    if (lane == 0) {
        for (int k2 = cnt0; k2 < 16; ++k2) { idx0[t * 16 + k2] = first0; rel0[t * 16 + k2] = rf0; }
        for (int k2 = cnt1; k2 < 32; ++k2) { idx1[t * 32 + k2] = first1; rel1[t * 32 + k2] = rf1; }
    }
}

// ------------------------------------------------------------------
// gather layer0: bufB[o][j] = Z[idx_j][o] + Wxyz[o]·rel_j, + BN stats.
template <int TPW, int NJL, int NSL, int JBL>
__device__ __forceinline__ void gath_body(const GQ P, int bx, float* sm1, float* sm2) {
    const int jx = ((bx & 7) << (JBL - 3)) | (bx >> 3);
    const int tid = threadIdx.x;
    const int lane = tid & 63;
    const int wid = tid >> 6;
    const int q = lane >> 4;
    const int jl = lane & 15;
    const int wtile0 = (jx * 4 + wid) * TPW;

    int nidxA[TPW];
    ushort4 rlA[TPW];
    #pragma unroll
    for (int i = 0; i < TPW; ++i) {
        int jj = (wtile0 + i) * 16 + jl;
        nidxA[i] = P.idxb[jj];
        rlA[i] = P.relb[jj];
    }

    float wx[2][8], wy[2][8], wz[2][8];
    #pragma unroll
    for (int kb = 0; kb < 2; ++kb)
        #pragma unroll
        for (int e = 0; e < 8; ++e) {
            int o = kb * 32 + q * 8 + e;
            wx[kb][e] = P.W[(size_t)o * 67 + 0];
            wy[kb][e] = P.W[(size_t)o * 67 + 1];
            wz[kb][e] = P.W[(size_t)o * 67 + 2];
        }

    bf16x8 zr[TPW][2];
    #pragma unroll
    for (int i = 0; i < TPW; ++i) {
        int jj = (wtile0 + i) * 16 + jl;
        int b = jj >> (NSL + 10);
        size_t nn = (size_t)b * N_ + nidxA[i];
        zr[i][0] = *(const bf16x8*)&P.Z[nn * 64 + q * 8];
        zr[i][1] = *(const bf16x8*)&P.Z[nn * 64 + 32 + q * 8];
    }

    float s1g[2][8], s2g[2][8];
    #pragma unroll
    for (int kb = 0; kb < 2; ++kb)
        #pragma unroll
        for (int e = 0; e < 8; ++e) { s1g[kb][e] = 0.f; s2g[kb][e] = 0.f; }

    #pragma unroll
    for (int i = 0; i < TPW; ++i) {
        int jj = (wtile0 + i) * 16 + jl;
        float rx = bf2f(rlA[i].x), ry = bf2f(rlA[i].y), rz = bf2f(rlA[i].z);
        #pragma unroll
        for (int kb = 0; kb < 2; ++kb) {
            unsigned int pk[4];
            #pragma unroll
            for (int e2 = 0; e2 < 4; ++e2) {
                float vv[2];
                #pragma unroll
                for (int h = 0; h < 2; ++h) {
                    int e = e2 * 2 + h;
                    float v = bf2f((unsigned short)zr[i][kb][e]);
                    v = fmaf(wx[kb][e], rx, v);
                    v = fmaf(wy[kb][e], ry, v);
                    v = fmaf(wz[kb][e], rz, v);
                    s1g[kb][e] += v;
                    s2g[kb][e] = fmaf(v, v, s2g[kb][e]);
                    vv[h] = v;
                }
                pk[e2] = cvt_pk(vv[0], vv[1]);
            }
            *(uint4*)&P.Xp[((size_t)(((kb * 4 + q) << NJL) + jj)) * 8] =
                make_uint4(pk[0], pk[1], pk[2], pk[3]);
        }
    }

    #pragma unroll
    for (int kb = 0; kb < 2; ++kb)
        #pragma unroll
        for (int e = 0; e < 8; ++e) {
            float v1 = s1g[kb][e], v2 = s2g[kb][e];
            v1 += __shfl_xor(v1, 1); v2 += __shfl_xor(v2, 1);
            v1 += __shfl_xor(v1, 2); v2 += __shfl_xor(v2, 2);
            v1 += __shfl_xor(v1, 4); v2 += __shfl_xor(v2, 4);
            v1 += __shfl_xor(v1, 8); v2 += __shfl_xor(v2, 8);
            s1g[kb][e] = v1; s2g[kb][e] = v2;
        }
    if (jl == 0) {
        #pragma unroll
        for (int kb = 0; kb < 2; ++kb)
            #pragma unroll
            for (int e = 0; e < 8; ++e) {
                int o = kb * 32 + q * 8 + e;
                sm1[wid * 64 + o] = s1g[kb][e];
                sm2[wid * 64 + o] = s2g[kb][e];
            }
    }
    __syncthreads();
    for (int o = tid; o < 64; o += 256) {
        P.pS[(size_t)o * PST + jx] = sm1[o] + sm1[64 + o] + sm1[128 + o] + sm1[192 + o];
        P.pS2[(size_t)o * PST + jx] = sm2[o] + sm2[64 + o] + sm2[128 + o] + sm2[192 + o];
    }
}

__global__ __launch_bounds__(256) void k_gath2(GQ p0, GQ p1, int split) {
    __shared__ float sm1[4 * 64], sm2[4 * 64];
    if ((int)blockIdx.x < split) gath_body<2, 16, 4, 9>(p0, blockIdx.x, sm1, sm2);
    else gath_body<2, 17, 5, 10>(p1, blockIdx.x - split, sm1, sm2);
}

// ------------------------------------------------------------------
// layer-1 streaming MFMA GEMM body (NPH phases x 64 j, double-buffered
// global_load_lds staging, BN folded).
template <int KB, int OT, int NPH, int NJL, int JXL>
__device__ __forceinline__ void mm_body(const MMQ P, int bx,
                                        unsigned short* Wa, unsigned short* XL,
                                        float* sm1, float* sm2) {
    constexpr int KB4 = KB * 4;
    const int oy = bx >> JXL;
    const int jxr = bx & ((1 << JXL) - 1);
    const int jx = ((jxr & 7) << (JXL - 3)) | (jxr >> 3);
    const int tid = threadIdx.x;
    const int lane = tid & 63;
    const int wid = tid >> 6;
    const int q = lane >> 4;
    const int jl = lane & 15;
    const int oybase = oy * OT * 16;
    const int jbase = jx * (NPH * 64);

    auto STAGE = [&](int buf, int p) {
        #pragma unroll
        for (int c2 = 0; c2 < KB; ++c2) {
            int chunk = wid * KB + c2;
            const unsigned short* gsrc =
                P.Xp + ((size_t)((chunk << NJL) + jbase + p * 64 + lane)) * 8;
            unsigned short* ldst = XL + ((size_t)(buf * KB4 + chunk) * 64) * 8;
            __builtin_amdgcn_global_load_lds((gk_gvoid*)gsrc, (gk_svoid*)ldst, 16, 0, 0);
        }
    };

    STAGE(0, 0);

    for (int s = tid; s < KB * OT * 64; s += 256) {
        int kb = s / (OT * 64);
        int r = s - kb * (OT * 64);
        int ot = r >> 6;
        int sl = r & 63;
        int o = oybase + ot * 16 + (sl & 15);
        int cbase = kb * 32 + (sl >> 4) * 8;
        unsigned int pk[4];
        #pragma unroll
        for (int e2 = 0; e2 < 4; ++e2) {
            int c0 = cbase + e2 * 2, c1 = c0 + 1;
            float w0 = (c0 < P.cin) ? P.W[(size_t)o * P.cin + c0] * P.ssin[c0 * 2 + 0] : 0.f;
            float w1 = (c1 < P.cin) ? P.W[(size_t)o * P.cin + c1] * P.ssin[c1 * 2 + 0] : 0.f;
            pk[e2] = (unsigned int)f2bf(w0) | ((unsigned int)f2bf(w1) << 16);
        }
        *(uint4*)&Wa[(size_t)s * 8] = make_uint4(pk[0], pk[1], pk[2], pk[3]);
    }
    __syncthreads();

    bf16x8 a[KB][OT];
    #pragma unroll
    for (int kb = 0; kb < KB; ++kb)
        #pragma unroll
        for (int ot = 0; ot < OT; ++ot)
            a[kb][ot] = *(const bf16x8*)&Wa[((kb * OT + ot) * 64 + lane) * 8];

    float tt[KB][8];
    #pragma unroll
    for (int kb = 0; kb < KB; ++kb)
        #pragma unroll
        for (int e = 0; e < 8; ++e) {
            int c = kb * 32 + q * 8 + e;
            tt[kb][e] = (c < P.cin) ? P.ssin[c * 2 + 1] : 0.f;
        }

    float s1_[OT][4], s2_[OT][4];
    #pragma unroll
    for (int ot = 0; ot < OT; ++ot)
        #pragma unroll
        for (int r = 0; r < 4; ++r) { s1_[ot][r] = 0.f; s2_[ot][r] = 0.f; }

    #pragma unroll
    for (int p = 0; p < NPH; ++p) {
        if (p + 1 < NPH) STAGE((p + 1) & 1, p + 1);
        const int buf = p & 1;
        const int jj = jbase + p * 64 + wid * 16 + jl;

        f32x4 acc[OT];
        #pragma unroll
        for (int ot = 0; ot < OT; ++ot) acc[ot] = (f32x4){0.f, 0.f, 0.f, 0.f};

        #pragma unroll
        for (int kb = 0; kb < KB; ++kb) {
            bf16x8 bf = *(const bf16x8*)&XL[((size_t)(buf * KB4 + kb * 4 + q) * 64 + wid * 16 + jl) * 8];
            union { bf16x8 v; unsigned int u[4]; } in, outp;
            in.v = bf;
            #pragma unroll
            for (int wd = 0; wd < 4; ++wd) {
                float lo = __uint_as_float(in.u[wd] << 16);
                float hi = __uint_as_float(in.u[wd] & 0xffff0000u);
                lo = fmaxf(lo + tt[kb][2 * wd], 0.f);
                hi = fmaxf(hi + tt[kb][2 * wd + 1], 0.f);
                outp.u[wd] = cvt_pk(lo, hi);
            }
            bf = outp.v;
            #pragma unroll
            for (int ot = 0; ot < OT; ++ot)
                acc[ot] = __builtin_amdgcn_mfma_f32_16x16x32_bf16(a[kb][ot], bf, acc[ot], 0, 0, 0);
        }

        #pragma unroll
        for (int ot = 0; ot < OT; ++ot)
            #pragma unroll
            for (int r = 0; r < 4; ++r) {
                float v = acc[ot][r];
                s1_[ot][r] += v;
                s2_[ot][r] = fmaf(v, v, s2_[ot][r]);
            }

        #pragma unroll
        for (int ot = 0; ot < OT; ++ot) {
            int o0 = oybase + ot * 16 + q * 4;
            *(uint2*)&P.Yp[((size_t)(((o0 >> 3) << NJL) + jj)) * 8 + (o0 & 7)] =
                make_uint2(cvt_pk(acc[ot][0], acc[ot][1]), cvt_pk(acc[ot][2], acc[ot][3]));
        }
        __syncthreads();
    }

    #pragma unroll
    for (int ot = 0; ot < OT; ++ot)
        #pragma unroll
        for (int r = 0; r < 4; ++r) {
            float v1 = s1_[ot][r], v2 = s2_[ot][r];
            v1 += __shfl_xor(v1, 1); v2 += __shfl_xor(v2, 1);
            v1 += __shfl_xor(v1, 2); v2 += __shfl_xor(v2, 2);
            v1 += __shfl_xor(v1, 4); v2 += __shfl_xor(v2, 4);
            v1 += __shfl_xor(v1, 8); v2 += __shfl_xor(v2, 8);
            s1_[ot][r] = v1; s2_[ot][r] = v2;
        }
    if (jl == 0) {
        #pragma unroll
        for (int ot = 0; ot < OT; ++ot)
            #pragma unroll
            for (int r = 0; r < 4; ++r) {
                sm1[wid * (OT * 16) + ot * 16 + q * 4 + r] = s1_[ot][r];
                sm2[wid * (OT * 16) + ot * 16 + q * 4 + r] = s2_[ot][r];
            }
    }
    __syncthreads();
    for (int o = tid; o < OT * 16; o += 256) {
        float a1 = sm1[o] + sm1[OT * 16 + o] + sm1[2 * OT * 16 + o] + sm1[3 * OT * 16 + o];
        float a2 = sm2[o] + sm2[OT * 16 + o] + sm2[2 * OT * 16 + o] + sm2[3 * OT * 16 + o];
        P.pS[(size_t)(oybase + o) * PST + jx] = a1;
        P.pS2[(size_t)(oybase + o) * PST + jx] = a2;
    }
}

template <int KB0, int OT0, int NJL0, int JXL0,
          int KB1, int OT1, int NJL1, int JXL1, int NPH>
__global__ __launch_bounds__(256) void k_mm2(MMQ p0, MMQ p1, int split) {
    constexpr int WAMAX = ((KB0 * OT0 > KB1 * OT1) ? KB0 * OT0 : KB1 * OT1) * 512;
    constexpr int KBMAX = (KB0 > KB1) ? KB0 : KB1;
    constexpr int XLSZ = 2 * KBMAX * 4 * 64 * 8;
    constexpr int OTMAX = (OT0 > OT1) ? OT0 : OT1;
    __shared__ __align__(16) unsigned short Wa[WAMAX];
    __shared__ __align__(16) unsigned short XL[XLSZ];
    __shared__ float sm1[4 * OTMAX * 16], sm2[4 * OTMAX * 16];
    if ((int)blockIdx.x < split)
        mm_body<KB0, OT0, NPH, NJL0, JXL0>(p0, blockIdx.x, Wa, XL, sm1, sm2);
    else
        mm_body<KB1, OT1, NPH, NJL1, JXL1>(p1, blockIdx.x - split, Wa, XL, sm1, sm2);
}

// ------------------------------------------------------------------
// layer-2 POOL GEMM with SWAPPED MFMA OPERANDS: mfma(X_frag, W_frag) so the
// output is transposed — each lane holds 4 j's of ONE o (o = lane&15).
// Max-pool over j then costs 3 in-lane fmax + 2 shfl_xor.
// Phase = 128 j; wave owns 32 j (= one ns=32 group -> in-wave pooling).
template <int KB, int OT, int NPH, int NSPOOL, int NJL, int JXL>
__device__ __forceinline__ void mmp_body(const MMQ P, int bx,
                                         unsigned short* Wa, unsigned short* XL,
                                         float* sm1, float* sm2) {
    constexpr int KB4 = KB * 4;
    const int oy = bx >> JXL;
    const int jxr = bx & ((1 << JXL) - 1);
    const int jx = ((jxr & 7) << (JXL - 3)) | (jxr >> 3);
    const int tid = threadIdx.x;
    const int lane = tid & 63;
    const int wid = tid >> 6;
    const int q = lane >> 4;
    const int jl = lane & 15;
    const int oybase = oy * OT * 16;
    const int jbase = jx * (NPH * 128);

    auto STAGE = [&](int buf, int p) {
        #pragma unroll
        for (int s0 = 0; s0 < 2 * KB; ++s0) {
            int s = wid + 4 * s0;
            int chunk = s >> 1;
            int half = s & 1;
            const unsigned short* gsrc =
                P.Xp + ((size_t)((chunk << NJL) + jbase + p * 128 + half * 64 + lane)) * 8;
            unsigned short* ldst = XL + ((size_t)((buf * KB4 + chunk) * 128 + half * 64)) * 8;
            __builtin_amdgcn_global_load_lds((gk_gvoid*)gsrc, (gk_svoid*)ldst, 16, 0, 0);
        }
    };

    STAGE(0, 0);

    // W staging with BN scale folded
    for (int s = tid; s < KB * OT * 64; s += 256) {
        int kb = s / (OT * 64);
        int r = s - kb * (OT * 64);
        int ot = r >> 6;
        int sl = r & 63;
        int o = oybase + ot * 16 + (sl & 15);
        int cbase = kb * 32 + (sl >> 4) * 8;
        unsigned int pk[4];
        #pragma unroll
        for (int e2 = 0; e2 < 4; ++e2) {
            int c0 = cbase + e2 * 2, c1 = c0 + 1;
            float w0 = (c0 < P.cin) ? P.W[(size_t)o * P.cin + c0] * P.ssin[c0 * 2 + 0] : 0.f;
            float w1 = (c1 < P.cin) ? P.W[(size_t)o * P.cin + c1] * P.ssin[c1 * 2 + 0] : 0.f;
            pk[e2] = (unsigned int)f2bf(w0) | ((unsigned int)f2bf(w1) << 16);
        }
        *(uint4*)&Wa[(size_t)s * 8] = make_uint4(pk[0], pk[1], pk[2], pk[3]);
    }
    __syncthreads();

    bf16x8 a[KB][OT];
    #pragma unroll
    for (int kb = 0; kb < KB; ++kb)
        #pragma unroll
        for (int ot = 0; ot < OT; ++ot)
            a[kb][ot] = *(const bf16x8*)&Wa[((kb * OT + ot) * 64 + lane) * 8];

    float tt[KB][8];
    #pragma unroll
    for (int kb = 0; kb < KB; ++kb)
        #pragma unroll
        for (int e = 0; e < 8; ++e) {
            int c = kb * 32 + q * 8 + e;
            tt[kb][e] = (c < P.cin) ? P.ssin[c * 2 + 1] : 0.f;
        }

    float s1_[OT][4], s2_[OT][4];
    #pragma unroll
    for (int ot = 0; ot < OT; ++ot)
        #pragma unroll
        for (int r = 0; r < 4; ++r) { s1_[ot][r] = 0.f; s2_[ot][r] = 0.f; }

    #pragma unroll
    for (int p = 0; p < NPH; ++p) {
        if (p + 1 < NPH) STAGE((p + 1) & 1, p + 1);
        const int buf = p & 1;
        float pm[2][OT];

        #pragma unroll
        for (int t2 = 0; t2 < 2; ++t2) {
            f32x4 acc[OT];
            #pragma unroll
            for (int ot = 0; ot < OT; ++ot) acc[ot] = (f32x4){0.f, 0.f, 0.f, 0.f};

            #pragma unroll
            for (int kb = 0; kb < KB; ++kb) {
                bf16x8 bf = *(const bf16x8*)&XL[((size_t)((buf * KB4 + kb * 4 + q) * 128 +
                                                          wid * 32 + t2 * 16 + jl)) * 8];
                union { bf16x8 v; unsigned int u[4]; } in, outp;
                in.v = bf;
                #pragma unroll
                for (int wd = 0; wd < 4; ++wd) {
                    float lo = __uint_as_float(in.u[wd] << 16);
                    float hi = __uint_as_float(in.u[wd] & 0xffff0000u);
                    lo = fmaxf(lo + tt[kb][2 * wd], 0.f);
                    hi = fmaxf(hi + tt[kb][2 * wd + 1], 0.f);
                    outp.u[wd] = cvt_pk(lo, hi);
                }
                bf = outp.v;
                #pragma unroll
                for (int ot = 0; ot < OT; ++ot)
                    acc[ot] = __builtin_amdgcn_mfma_f32_16x16x32_bf16(bf, a[kb][ot], acc[ot], 0, 0, 0);
            }

            #pragma unroll
            for (int ot = 0; ot < OT; ++ot) {
                float mx = fmaxf(fmaxf(acc[ot][0], acc[ot][1]), fmaxf(acc[ot][2], acc[ot][3]));
                #pragma unroll
                for (int r = 0; r < 4; ++r) {
                    float v = acc[ot][r];
                    s1_[ot][r] += v;
                    s2_[ot][r] = fmaf(v, v, s2_[ot][r]);
                }
                mx = fmaxf(mx, __shfl_xor(mx, 16));
                mx = fmaxf(mx, __shfl_xor(mx, 32));
                pm[t2][ot] = mx;
            }
        }

        int j0 = jbase + p * 128 + wid * 32;
        if (NSPOOL == 32) {
            if (lane < 16) {
                int bm = j0 >> 5;
                #pragma unroll
                for (int ot = 0; ot < OT; ++ot)
                    P.Ymax[(size_t)bm * 128 + oybase + ot * 16 + jl] = fmaxf(pm[0][ot], pm[1][ot]);
            }
        } else {
            if (lane < 16) {
                int bm0 = j0 >> 4;
                #pragma unroll
                for (int t2 = 0; t2 < 2; ++t2)
                    #pragma unroll
                    for (int ot = 0; ot < OT; ++ot)
                        P.Ymax[(size_t)(bm0 + t2) * 128 + oybase + ot * 16 + jl] = pm[t2][ot];
            }
        }
        __syncthreads();
    }

    #pragma unroll
    for (int ot = 0; ot < OT; ++ot) {
        float v1 = s1_[ot][0] + s1_[ot][1] + s1_[ot][2] + s1_[ot][3];
        float v2 = s2_[ot][0] + s2_[ot][1] + s2_[ot][2] + s2_[ot][3];
        v1 += __shfl_xor(v1, 16); v2 += __shfl_xor(v2, 16);
        v1 += __shfl_xor(v1, 32); v2 += __shfl_xor(v2, 32);
        if (lane < 16) {
            sm1[wid * (OT * 16) + ot * 16 + jl] = v1;
            sm2[wid * (OT * 16) + ot * 16 + jl] = v2;
        }
    }
    __syncthreads();
    for (int o = tid; o < OT * 16; o += 256) {
        float a1 = sm1[o] + sm1[OT * 16 + o] + sm1[2 * OT * 16 + o] + sm1[3 * OT * 16 + o];
        float a2 = sm2[o] + sm2[OT * 16 + o] + sm2[2 * OT * 16 + o] + sm2[3 * OT * 16 + o];
        P.pS[(size_t)(oybase + o) * PST + jx] = a1;
        P.pS2[(size_t)(oybase + o) * PST + jx] = a2;
    }
}

template <int KB0, int OT0, int NJL0, int NSP0, int JXL0,
          int KB1, int OT1, int NJL1, int NSP1, int JXL1, int NPH>
__global__ __launch_bounds__(256) void k_mmp(MMQ p0, MMQ p1, int split) {
    constexpr int WAMAX = ((KB0 * OT0 > KB1 * OT1) ? KB0 * OT0 : KB1 * OT1) * 512;
    constexpr int KBMAX = (KB0 > KB1) ? KB0 : KB1;
    constexpr int XLSZ = 2 * KBMAX * 4 * 128 * 8;
    constexpr int OTMAX = (OT0 > OT1) ? OT0 : OT1;
    __shared__ __align__(16) unsigned short Wa[WAMAX];
    __shared__ __align__(16) unsigned short XL[XLSZ];
    __shared__ float sm1[4 * OTMAX * 16], sm2[4 * OTMAX * 16];
    if ((int)blockIdx.x < split)
        mmp_body<KB0, OT0, NPH, NSP0, NJL0, JXL0>(p0, blockIdx.x, Wa, XL, sm1, sm2);
    else
        mmp_body<KB1, OT1, NPH, NSP1, NJL1, JXL1>(p1, blockIdx.x - split, Wa, XL, sm1, sm2);
}

// ------------------------------------------------------------------
// merged fin.  mode 0: ss = (scale, shift/scale); mode 1: ss = (scale, shift).
__global__ __launch_bounds__(64) void k_fin2(const float* __restrict__ pSa, const float* __restrict__ pS2a,
                                             const float* __restrict__ ga, const float* __restrict__ ba,
                                             float* __restrict__ ssa, int ca, int gxa, float invNa,
                                             const float* __restrict__ pSb, const float* __restrict__ pS2b,
                                             const float* __restrict__ gb, const float* __restrict__ bbv,
                                             float* __restrict__ ssb, int gxb, float invNb, int mode) {
    int o = blockIdx.x;
    const float *pS, *pS2, *g, *bt;
    float* ss;
    int gx;
    float invN;
    if (o < ca) { pS = pSa; pS2 = pS2a; g = ga; bt = ba; ss = ssa; gx = gxa; invN = invNa; }
    else { o -= ca; pS = pSb; pS2 = pS2b; g = gb; bt = bbv; ss = ssb; gx = gxb; invN = invNb; }
    int l = threadIdx.x;
    float s = 0.f, s2 = 0.f;
    for (int i = l; i < gx; i += 64) {
        s += pS[(size_t)o * PST + i];
        s2 += pS2[(size_t)o * PST + i];
    }
    #pragma unroll
    for (int off = 1; off < 64; off <<= 1) {
        s += __shfl_xor(s, off, 64);
        s2 += __shfl_xor(s2, off, 64);
    }
    if (l == 0) {
        float mean = s * invN;
        float var = s2 * invN - mean * mean;
        float scale = g[o] / sqrtf(var + 1e-5f);
        float shift = bt[o] - mean * scale;
        ss[o * 2 + 0] = scale;
        ss[o * 2 + 1] = mode ? shift : shift / scale;
    }
}

// ------------------------------------------------------------------
__global__ __launch_bounds__(256) void k_poolfin2(const float* __restrict__ Ymax0, const float* __restrict__ ss0,
                                                  const float* __restrict__ Ymax1, const float* __restrict__ ss1,
                                                  float* __restrict__ out) {
    __shared__ float T[128][65];
    int blk = blockIdx.x;
    const float* Ymax;
    const float* ss;
    int o_off;
    if (blk < 64) { Ymax = Ymax0; ss = ss0; o_off = 0; }
    else { blk -= 64; Ymax = Ymax1; ss = ss1; o_off = 128; }
    int b = blk >> 4, mc = blk & 15;
    int bm0 = b * M_ + mc * 64;
    for (int s = threadIdx.x; s < 64 * 32; s += 256) {
        int row = s >> 5;
        int c4 = s & 31;
        float4 v = *(const float4*)&Ymax[(size_t)(bm0 + row) * 128 + c4 * 4];
        T[c4 * 4 + 0][row] = v.x;
        T[c4 * 4 + 1][row] = v.y;
        T[c4 * 4 + 2][row] = v.z;
        T[c4 * 4 + 3][row] = v.w;
    }
    __syncthreads();
    for (int s = threadIdx.x; s < 128 * 16; s += 256) {
        int o = s >> 4, m4 = s & 15;
        float scv = ss[o * 2 + 0], shv = ss[o * 2 + 1];
        float4 v = make_float4(T[o][m4 * 4], T[o][m4 * 4 + 1], T[o][m4 * 4 + 2], T[o][m4 * 4 + 3]);
        v.x = fmaxf(fmaf(v.x, scv, shv), 0.f);
        v.y = fmaxf(fmaf(v.y, scv, shv), 0.f);
        v.z = fmaxf(fmaf(v.z, scv, shv), 0.f);
        v.w = fmaxf(fmaf(v.w, scv, shv), 0.f);
        *(float4*)&out[OUT_XYZ_ELEMS + ((size_t)(b * 256 + o_off + o)) * M_ + mc * 64 + m4 * 4] = v;
    }
}

// ------------------------------------------------------------------
extern "C" void kernel_launch(void* const* d_in, const int* in_sizes, int n_in,
                              void* d_out, int out_size, void* d_ws, size_t ws_size,
                              hipStream_t stream) {
    const float* xyz = (const float*)d_in[0];
    const float* feats = (const float*)d_in[1];
    const int* inds = (const int*)d_in[2];
    const float* w[2][3];
    const float* gg[2][3];
    const float* bb[2][3];
    int k = 3;
    for (int i = 0; i < 2; ++i)
        for (int l = 0; l < 3; ++l) {
            w[i][l] = (const float*)d_in[k++];
            gg[i][l] = (const float*)d_in[k++];
            bb[i][l] = (const float*)d_in[k++];
        }
    float* out = (float*)d_out;

    const int Nj0 = B_ * M_ * 16;  // 65536 = 1<<16
    const int Nj1 = B_ * M_ * 32;  // 131072 = 1<<17

    unsigned short* Z0 = (unsigned short*)d_ws;
    unsigned short* Z1 = Z0 + (size_t)B_ * N_ * 64;
    unsigned short* bufB0 = Z1 + (size_t)B_ * N_ * 64;
    unsigned short* bufA0 = bufB0 + (size_t)8 * Nj0 * 8;
    unsigned short* bufB1 = bufA0 + (size_t)12 * Nj0 * 8;
    unsigned short* bufA1 = bufB1 + (size_t)8 * Nj1 * 8;
    float* Ymax0 = (float*)(bufA1 + (size_t)12 * Nj1 * 8);
    float* Ymax1 = Ymax0 + (size_t)B_ * M_ * 128;
    float* pS0 = Ymax1 + (size_t)B_ * M_ * 128;
    float* pS2_0 = pS0 + (size_t)128 * PST;
    float* pS1 = pS2_0 + (size_t)128 * PST;
    float* pS2_1 = pS1 + (size_t)128 * PST;
    float* ss0 = pS2_1 + (size_t)128 * PST;
    float* ss1 = ss0 + 256;
    int* idx0 = (int*)(ss1 + 256);
    int* idx1 = idx0 + Nj0;
    ushort4* rel0 = (ushort4*)(idx1 + Nj1);
    ushort4* rel1 = rel0 + Nj0;

    const float inv0 = 1.f / Nj0, inv1 = 1.f / Nj1;

    // 1) prep: transpose+dense-L0 (blocks 0-1023) and dual ball (1024-2047)
    k_prep<<<2048, 256, 0, stream>>>(xyz, feats, inds, w[0][0], w[1][0], Z0, Z1, out,
                                     idx0, rel0, idx1, rel1,
                                     (float)(0.4 * 0.4), (float)(0.8 * 0.8));

    // 2) gather + xyz-add + stats -> bufB
    GQ g0{}, g1{};
    g0.W = w[0][0]; g0.Z = Z0; g0.idxb = idx0; g0.relb = rel0;
    g0.Xp = bufB0; g0.pS = pS0; g0.pS2 = pS2_0;
    g1.W = w[1][0]; g1.Z = Z1; g1.idxb = idx1; g1.relb = rel1;
    g1.Xp = bufB1; g1.pS = pS1; g1.pS2 = pS2_1;
    k_gath2<<<1536, 256, 0, stream>>>(g0, g1, 512);
    k_fin2<<<128, 64, 0, stream>>>(pS0, pS2_0, gg[0][0], bb[0][0], ss0, 64, 512, inv0,
                                   pS1, pS2_1, gg[1][0], bb[1][0], ss1, 1024, inv1, 0);

    // 3) layer1: NPH=4 (256 j/block).  s0: KB2 OT4 (64ch, 256 jx);
    //            s1: KB2 OT6 (96ch, 512 jx).
    MMQ b0{}, b1{};
    b0.W = w[0][1]; b0.Xp = bufB0; b0.ssin = ss0; b0.Yp = bufA0;
    b0.pS = pS0; b0.pS2 = pS2_0; b0.cin = 64;
    b1.W = w[1][1]; b1.Xp = bufB1; b1.ssin = ss1; b1.Yp = bufA1;
    b1.pS = pS1; b1.pS2 = pS2_1; b1.cin = 64;
    k_mm2<2, 4, 16, 8,  2, 6, 17, 9,  4>
        <<<768, 256, 0, stream>>>(b0, b1, 256);
    k_fin2<<<160, 64, 0, stream>>>(pS0, pS2_0, gg[0][1], bb[0][1], ss0, 64, 256, inv0,
                                   pS1, pS2_1, gg[1][1], bb[1][1], ss1, 512, inv1, 0);

    // 4) layer2 POOL (swapped-operand): NPH=4, 512 j/block, s1 FIRST.
    //    s1: KB3 OT4 oy2 (256 jx -> 512 blocks); s0: KB2 OT4 oy2 (128 jx -> 256).
    MMQ c0{}, c1{};
    c0.W = w[0][2]; c0.Xp = bufA0; c0.ssin = ss0; c0.Ymax = Ymax0;
    c0.pS = pS0; c0.pS2 = pS2_0; c0.cin = 64;
    c1.W = w[1][2]; c1.Xp = bufA1; c1.ssin = ss1; c1.Ymax = Ymax1;
    c1.pS = pS1; c1.pS2 = pS2_1; c1.cin = 96;
    k_mmp<3, 4, 17, 32, 8,  2, 4, 16, 16, 7,  4>
        <<<768, 256, 0, stream>>>(c1, c0, 512);
    k_fin2<<<256, 64, 0, stream>>>(pS0, pS2_0, gg[0][2], bb[0][2], ss0, 128, 128, inv0,
                                   pS1, pS2_1, gg[1][2], bb[1][2], ss1, 256, inv1, 1);

    // 5) final BN+ReLU + transpose
    k_poolfin2<<<128, 256, 0, stream>>>(Ymax0, ss0, Ymax1, ss1, out);
}

// Round 18
// 114.946 us; speedup vs baseline: 5.8361x; 1.0459x over previous
//
#include <hip/hip_runtime.h>
#include <math.h>

#define B_ 4
#define N_ 16384
#define M_ 1024
#define C_ 64

// output layout (floats): new_xyz [B*M*3] | feats [B*256*M] | inds [B*M]
#define OUT_XYZ_ELEMS (B_ * M_ * 3)
#define OUT_FEAT_ELEMS (B_ * 256 * M_)
#define PST 1024  // partial-stats stride (>= max j-blocks)

typedef __attribute__((ext_vector_type(8))) short bf16x8;
typedef __attribute__((ext_vector_type(4))) float f32x4;
typedef __attribute__((address_space(1))) const void gk_gvoid;
typedef __attribute__((address_space(3))) void gk_svoid;

__device__ __forceinline__ unsigned short f2bf(float f) {
    unsigned int u = __float_as_uint(f);
    u += 0x7fffu + ((u >> 16) & 1u);
    return (unsigned short)(u >> 16);
}
__device__ __forceinline__ float bf2f(unsigned short h) {
    return __uint_as_float(((unsigned int)h) << 16);
}
// hardware packed f32x2 -> bf16x2 (RNE), src0 -> low half
__device__ __forceinline__ unsigned int cvt_pk(float lo, float hi) {
    unsigned int r;
    asm("v_cvt_pk_bf16_f32 %0, %1, %2" : "=v"(r) : "v"(lo), "v"(hi));
    return r;
}

struct MMQ {
    const float* W;
    const unsigned short* Xp;
    const float* ssin;
    unsigned short* Yp;
    float* Ymax;
    float* pS;
    float* pS2;
    int cin;
};

struct GQ {
    const float* W;
    const unsigned short* Z;
    const int* idxb;
    const ushort4* relb;
    unsigned short* Xp;
    float* pS;
    float* pS2;
};

// ------------------------------------------------------------------
// prep: blocks [0,1024): transpose feats tile into LDS AND compute the
// dense layer0 feature GEMM for both scales straight from LDS.
// blocks [1024,2048): dual-radius ball query + center gather.
__global__ __launch_bounds__(256) void k_prep(const float* __restrict__ xyz,
                                              const float* __restrict__ feats,
                                              const int* __restrict__ inds,
                                              const float* __restrict__ W0,
                                              const float* __restrict__ W1,
                                              unsigned short* __restrict__ Z0,
                                              unsigned short* __restrict__ Z1,
                                              float* __restrict__ out,
                                              int* __restrict__ idx0, ushort4* __restrict__ rel0,
                                              int* __restrict__ idx1, ushort4* __restrict__ rel1,
                                              float r0sq, float r1sq) {
    __shared__ __align__(16) unsigned short T[64][72];
    __shared__ __align__(16) unsigned short Wa2[2 * 2 * 4 * 64 * 8];
    int bx = blockIdx.x;
    const int tid = threadIdx.x;
    if (bx < 1024) {
        int b = bx >> 8;
        int n0 = (bx & 255) << 6;
        int tn = tid & 63;
        int c0 = tid >> 6;
        const float* fp = feats + (size_t)b * C_ * N_ + n0 + tn;
        #pragma unroll
        for (int it = 0; it < 16; ++it) {
            int c = it * 4 + c0;
            T[c][tn] = f2bf(fp[(size_t)c * N_]);
        }
        for (int s = tid; s < 2 * 2 * 4 * 64; s += 256) {
            int scale = s >> 9;
            int r = s & 511;
            int kb = r >> 8;
            int ot = (r >> 6) & 3;
            int sl = r & 63;
            int o = ot * 16 + (sl & 15);
            int cb = kb * 32 + (sl >> 4) * 8;
            const float* W = scale ? W1 : W0;
            unsigned int pk[4];
            #pragma unroll
            for (int e2 = 0; e2 < 4; ++e2)
                pk[e2] = (unsigned int)f2bf(W[(size_t)o * 67 + 3 + cb + e2 * 2]) |
                         ((unsigned int)f2bf(W[(size_t)o * 67 + 3 + cb + e2 * 2 + 1]) << 16);
            *(uint4*)&Wa2[(size_t)s * 8] = make_uint4(pk[0], pk[1], pk[2], pk[3]);
        }
        __syncthreads();

        const int lane = tid & 63;
        const int wid = tid >> 6;
        const int q = lane >> 4;
        const int jl = lane & 15;
        bf16x8 bfr[2];
        #pragma unroll
        for (int kb = 0; kb < 2; ++kb) {
            union { bf16x8 v; unsigned short u[8]; } tmp;
            #pragma unroll
            for (int e = 0; e < 8; ++e) tmp.u[e] = T[kb * 32 + q * 8 + e][wid * 16 + jl];
            bfr[kb] = tmp.v;
        }
        size_t n = (size_t)b * N_ + n0 + wid * 16 + jl;
        #pragma unroll
        for (int sc2 = 0; sc2 < 2; ++sc2) {
            unsigned short* Z = sc2 ? Z1 : Z0;
            f32x4 acc[4];
            #pragma unroll
            for (int ot = 0; ot < 4; ++ot) acc[ot] = (f32x4){0.f, 0.f, 0.f, 0.f};
            #pragma unroll
            for (int kb = 0; kb < 2; ++kb) {
                #pragma unroll
                for (int ot = 0; ot < 4; ++ot) {
                    bf16x8 a = *(const bf16x8*)&Wa2[(((sc2 * 2 + kb) * 4 + ot) * 64 + lane) * 8];
                    acc[ot] = __builtin_amdgcn_mfma_f32_16x16x32_bf16(a, bfr[kb], acc[ot], 0, 0, 0);
                }
            }
            #pragma unroll
            for (int ot = 0; ot < 4; ++ot)
                *(uint2*)&Z[n * 64 + ot * 16 + q * 4] =
                    make_uint2(cvt_pk(acc[ot][0], acc[ot][1]), cvt_pk(acc[ot][2], acc[ot][3]));
        }
        return;
    }
    // ---- ball region ----
    int lane = tid & 63;
    int t = (bx - 1024) * 4 + (tid >> 6);
    int b = t >> 10;
    int n0 = inds[t];
    const float* bp = xyz + (size_t)b * N_ * 3;
    float qx = bp[n0 * 3 + 0], qy = bp[n0 * 3 + 1], qz = bp[n0 * 3 + 2];
    if (lane == 0) {
        out[t * 3 + 0] = qx;
        out[t * 3 + 1] = qy;
        out[t * 3 + 2] = qz;
        out[OUT_XYZ_ELEMS + OUT_FEAT_ELEMS + t] = (float)n0;
    }
    int cnt0 = 0, cnt1 = 0, first0 = n0, first1 = n0;
    ushort4 rf0 = make_ushort4(0, 0, 0, 0), rf1 = make_ushort4(0, 0, 0, 0);
    for (int base = 0; base < N_ && (cnt0 < 16 || cnt1 < 32); base += 64) {
        int n = base + lane;
        float dx = __fsub_rn(bp[n * 3 + 0], qx);
        float dy = __fsub_rn(bp[n * 3 + 1], qy);
        float dz = __fsub_rn(bp[n * 3 + 2], qz);
        float d2 = __fadd_rn(__fadd_rn(__fmul_rn(dx, dx), __fmul_rn(dy, dy)), __fmul_rn(dz, dz));
        unsigned long long m1 = __ballot(d2 < r1sq);
        unsigned long long m0 = __ballot(d2 < r0sq);
        if (cnt1 >= 32) m1 &= m0;
        while (m1) {
            int bit = (int)__builtin_ctzll(m1);
            m1 &= m1 - 1;
            int nn = base + bit;
            float sx = __shfl(dx, bit), sy = __shfl(dy, bit), sz = __shfl(dz, bit);
            ushort4 r = make_ushort4(f2bf(sx), f2bf(sy), f2bf(sz), 0);
            if (cnt1 < 32) {
                if (cnt1 == 0) { first1 = nn; rf1 = r; }
                if (lane == 0) { idx1[t * 32 + cnt1] = nn; rel1[t * 32 + cnt1] = r; }
                cnt1++;
                if (cnt1 == 32) m1 &= m0;
            }
            if (cnt0 < 16 && ((m0 >> bit) & 1ull)) {
                if (cnt0 == 0) { first0 = nn; rf0 = r; }
                if (lane == 0) { idx0[t * 16 + cnt0] = nn; rel0[t * 16 + cnt0] = r; }
                cnt0++;
            }
            if (cnt1 >= 32 && cnt0 >= 16) break;
        }
    }
    if (lane == 0) {
        for (int k2 = cnt0; k2 < 16; ++k2) { idx0[t * 16 + k2] = first0; rel0[t * 16 + k2] = rf0; }
        for (int k2 = cnt1; k2 < 32; ++k2) { idx1[t * 32 + k2] = first1; rel1[t * 32 + k2] = rf1; }
    }
}

// ------------------------------------------------------------------
// gather layer0: bufB[o][j] = Z[idx_j][o] + Wxyz[o]·rel_j, + BN stats.
// TPW=4: 8 Z-gathers in flight per wave (latency-bound kernel -> 2x MLP).
template <int TPW, int NJL, int NSL, int JBL>
__device__ __forceinline__ void gath_body(const GQ P, int bx, float* sm1, float* sm2) {
    const int jx = ((bx & 7) << (JBL - 3)) | (bx >> 3);
    const int tid = threadIdx.x;
    const int lane = tid & 63;
    const int wid = tid >> 6;
    const int q = lane >> 4;
    const int jl = lane & 15;
    const int wtile0 = (jx * 4 + wid) * TPW;

    int nidxA[TPW];
    ushort4 rlA[TPW];
    #pragma unroll
    for (int i = 0; i < TPW; ++i) {
        int jj = (wtile0 + i) * 16 + jl;
        nidxA[i] = P.idxb[jj];
        rlA[i] = P.relb[jj];
    }

    float wx[2][8], wy[2][8], wz[2][8];
    #pragma unroll
    for (int kb = 0; kb < 2; ++kb)
        #pragma unroll
        for (int e = 0; e < 8; ++e) {
            int o = kb * 32 + q * 8 + e;
            wx[kb][e] = P.W[(size_t)o * 67 + 0];
            wy[kb][e] = P.W[(size_t)o * 67 + 1];
            wz[kb][e] = P.W[(size_t)o * 67 + 2];
        }

    bf16x8 zr[TPW][2];
    #pragma unroll
    for (int i = 0; i < TPW; ++i) {
        int jj = (wtile0 + i) * 16 + jl;
        int b = jj >> (NSL + 10);
        size_t nn = (size_t)b * N_ + nidxA[i];
        zr[i][0] = *(const bf16x8*)&P.Z[nn * 64 + q * 8];
        zr[i][1] = *(const bf16x8*)&P.Z[nn * 64 + 32 + q * 8];
    }

    float s1g[2][8], s2g[2][8];
    #pragma unroll
    for (int kb = 0; kb < 2; ++kb)
        #pragma unroll
        for (int e = 0; e < 8; ++e) { s1g[kb][e] = 0.f; s2g[kb][e] = 0.f; }

    #pragma unroll
    for (int i = 0; i < TPW; ++i) {
        int jj = (wtile0 + i) * 16 + jl;
        float rx = bf2f(rlA[i].x), ry = bf2f(rlA[i].y), rz = bf2f(rlA[i].z);
        #pragma unroll
        for (int kb = 0; kb < 2; ++kb) {
            unsigned int pk[4];
            #pragma unroll
            for (int e2 = 0; e2 < 4; ++e2) {
                float vv[2];
                #pragma unroll
                for (int h = 0; h < 2; ++h) {
                    int e = e2 * 2 + h;
                    float v = bf2f((unsigned short)zr[i][kb][e]);
                    v = fmaf(wx[kb][e], rx, v);
                    v = fmaf(wy[kb][e], ry, v);
                    v = fmaf(wz[kb][e], rz, v);
                    s1g[kb][e] += v;
                    s2g[kb][e] = fmaf(v, v, s2g[kb][e]);
                    vv[h] = v;
                }
                pk[e2] = cvt_pk(vv[0], vv[1]);
            }
            *(uint4*)&P.Xp[((size_t)(((kb * 4 + q) << NJL) + jj)) * 8] =
                make_uint4(pk[0], pk[1], pk[2], pk[3]);
        }
    }

    #pragma unroll
    for (int kb = 0; kb < 2; ++kb)
        #pragma unroll
        for (int e = 0; e < 8; ++e) {
            float v1 = s1g[kb][e], v2 = s2g[kb][e];
            v1 += __shfl_xor(v1, 1); v2 += __shfl_xor(v2, 1);
            v1 += __shfl_xor(v1, 2); v2 += __shfl_xor(v2, 2);
            v1 += __shfl_xor(v1, 4); v2 += __shfl_xor(v2, 4);
            v1 += __shfl_xor(v1, 8); v2 += __shfl_xor(v2, 8);
            s1g[kb][e] = v1; s2g[kb][e] = v2;
        }
    if (jl == 0) {
        #pragma unroll
        for (int kb = 0; kb < 2; ++kb)
            #pragma unroll
            for (int e = 0; e < 8; ++e) {
                int o = kb * 32 + q * 8 + e;
                sm1[wid * 64 + o] = s1g[kb][e];
                sm2[wid * 64 + o] = s2g[kb][e];
            }
    }
    __syncthreads();
    for (int o = tid; o < 64; o += 256) {
        P.pS[(size_t)o * PST + jx] = sm1[o] + sm1[64 + o] + sm1[128 + o] + sm1[192 + o];
        P.pS2[(size_t)o * PST + jx] = sm2[o] + sm2[64 + o] + sm2[128 + o] + sm2[192 + o];
    }
}

__global__ __launch_bounds__(256) void k_gath2(GQ p0, GQ p1, int split) {
    __shared__ float sm1[4 * 64], sm2[4 * 64];
    if ((int)blockIdx.x < split) gath_body<4, 16, 4, 8>(p0, blockIdx.x, sm1, sm2);
    else gath_body<4, 17, 5, 9>(p1, blockIdx.x - split, sm1, sm2);
}

// ------------------------------------------------------------------
// layer-1 streaming MFMA GEMM body (NPH phases x 64 j, double-buffered
// global_load_lds staging, BN folded).
template <int KB, int OT, int NPH, int NJL, int JXL>
__device__ __forceinline__ void mm_body(const MMQ P, int bx,
                                        unsigned short* Wa, unsigned short* XL,
                                        float* sm1, float* sm2) {
    constexpr int KB4 = KB * 4;
    const int oy = bx >> JXL;
    const int jxr = bx & ((1 << JXL) - 1);
    const int jx = ((jxr & 7) << (JXL - 3)) | (jxr >> 3);
    const int tid = threadIdx.x;
    const int lane = tid & 63;
    const int wid = tid >> 6;
    const int q = lane >> 4;
    const int jl = lane & 15;
    const int oybase = oy * OT * 16;
    const int jbase = jx * (NPH * 64);

    auto STAGE = [&](int buf, int p) {
        #pragma unroll
        for (int c2 = 0; c2 < KB; ++c2) {
            int chunk = wid * KB + c2;
            const unsigned short* gsrc =
                P.Xp + ((size_t)((chunk << NJL) + jbase + p * 64 + lane)) * 8;
            unsigned short* ldst = XL + ((size_t)(buf * KB4 + chunk) * 64) * 8;
            __builtin_amdgcn_global_load_lds((gk_gvoid*)gsrc, (gk_svoid*)ldst, 16, 0, 0);
        }
    };

    STAGE(0, 0);

    for (int s = tid; s < KB * OT * 64; s += 256) {
        int kb = s / (OT * 64);
        int r = s - kb * (OT * 64);
        int ot = r >> 6;
        int sl = r & 63;
        int o = oybase + ot * 16 + (sl & 15);
        int cbase = kb * 32 + (sl >> 4) * 8;
        unsigned int pk[4];
        #pragma unroll
        for (int e2 = 0; e2 < 4; ++e2) {
            int c0 = cbase + e2 * 2, c1 = c0 + 1;
            float w0 = (c0 < P.cin) ? P.W[(size_t)o * P.cin + c0] * P.ssin[c0 * 2 + 0] : 0.f;
            float w1 = (c1 < P.cin) ? P.W[(size_t)o * P.cin + c1] * P.ssin[c1 * 2 + 0] : 0.f;
            pk[e2] = (unsigned int)f2bf(w0) | ((unsigned int)f2bf(w1) << 16);
        }
        *(uint4*)&Wa[(size_t)s * 8] = make_uint4(pk[0], pk[1], pk[2], pk[3]);
    }
    __syncthreads();

    bf16x8 a[KB][OT];
    #pragma unroll
    for (int kb = 0; kb < KB; ++kb)
        #pragma unroll
        for (int ot = 0; ot < OT; ++ot)
            a[kb][ot] = *(const bf16x8*)&Wa[((kb * OT + ot) * 64 + lane) * 8];

    float tt[KB][8];
    #pragma unroll
    for (int kb = 0; kb < KB; ++kb)
        #pragma unroll
        for (int e = 0; e < 8; ++e) {
            int c = kb * 32 + q * 8 + e;
            tt[kb][e] = (c < P.cin) ? P.ssin[c * 2 + 1] : 0.f;
        }

    float s1_[OT][4], s2_[OT][4];
    #pragma unroll
    for (int ot = 0; ot < OT; ++ot)
        #pragma unroll
        for (int r = 0; r < 4; ++r) { s1_[ot][r] = 0.f; s2_[ot][r] = 0.f; }

    #pragma unroll
    for (int p = 0; p < NPH; ++p) {
        if (p + 1 < NPH) STAGE((p + 1) & 1, p + 1);
        const int buf = p & 1;
        const int jj = jbase + p * 64 + wid * 16 + jl;

        f32x4 acc[OT];
        #pragma unroll
        for (int ot = 0; ot < OT; ++ot) acc[ot] = (f32x4){0.f, 0.f, 0.f, 0.f};

        #pragma unroll
        for (int kb = 0; kb < KB; ++kb) {
            bf16x8 bf = *(const bf16x8*)&XL[((size_t)(buf * KB4 + kb * 4 + q) * 64 + wid * 16 + jl) * 8];
            union { bf16x8 v; unsigned int u[4]; } in, outp;
            in.v = bf;
            #pragma unroll
            for (int wd = 0; wd < 4; ++wd) {
                float lo = __uint_as_float(in.u[wd] << 16);
                float hi = __uint_as_float(in.u[wd] & 0xffff0000u);
                lo = fmaxf(lo + tt[kb][2 * wd], 0.f);
                hi = fmaxf(hi + tt[kb][2 * wd + 1], 0.f);
                outp.u[wd] = cvt_pk(lo, hi);
            }
            bf = outp.v;
            #pragma unroll
            for (int ot = 0; ot < OT; ++ot)
                acc[ot] = __builtin_amdgcn_mfma_f32_16x16x32_bf16(a[kb][ot], bf, acc[ot], 0, 0, 0);
        }

        #pragma unroll
        for (int ot = 0; ot < OT; ++ot)
            #pragma unroll
            for (int r = 0; r < 4; ++r) {
                float v = acc[ot][r];
                s1_[ot][r] += v;
                s2_[ot][r] = fmaf(v, v, s2_[ot][r]);
            }

        #pragma unroll
        for (int ot = 0; ot < OT; ++ot) {
            int o0 = oybase + ot * 16 + q * 4;
            *(uint2*)&P.Yp[((size_t)(((o0 >> 3) << NJL) + jj)) * 8 + (o0 & 7)] =
                make_uint2(cvt_pk(acc[ot][0], acc[ot][1]), cvt_pk(acc[ot][2], acc[ot][3]));
        }
        __syncthreads();
    }

    #pragma unroll
    for (int ot = 0; ot < OT; ++ot)
        #pragma unroll
        for (int r = 0; r < 4; ++r) {
            float v1 = s1_[ot][r], v2 = s2_[ot][r];
            v1 += __shfl_xor(v1, 1); v2 += __shfl_xor(v2, 1);
            v1 += __shfl_xor(v1, 2); v2 += __shfl_xor(v2, 2);
            v1 += __shfl_xor(v1, 4); v2 += __shfl_xor(v2, 4);
            v1 += __shfl_xor(v1, 8); v2 += __shfl_xor(v2, 8);
            s1_[ot][r] = v1; s2_[ot][r] = v2;
        }
    if (jl == 0) {
        #pragma unroll
        for (int ot = 0; ot < OT; ++ot)
            #pragma unroll
            for (int r = 0; r < 4; ++r) {
                sm1[wid * (OT * 16) + ot * 16 + q * 4 + r] = s1_[ot][r];
                sm2[wid * (OT * 16) + ot * 16 + q * 4 + r] = s2_[ot][r];
            }
    }
    __syncthreads();
    for (int o = tid; o < OT * 16; o += 256) {
        float a1 = sm1[o] + sm1[OT * 16 + o] + sm1[2 * OT * 16 + o] + sm1[3 * OT * 16 + o];
        float a2 = sm2[o] + sm2[OT * 16 + o] + sm2[2 * OT * 16 + o] + sm2[3 * OT * 16 + o];
        P.pS[(size_t)(oybase + o) * PST + jx] = a1;
        P.pS2[(size_t)(oybase + o) * PST + jx] = a2;
    }
}

template <int KB0, int OT0, int NJL0, int JXL0,
          int KB1, int OT1, int NJL1, int JXL1, int NPH>
__global__ __launch_bounds__(256) void k_mm2(MMQ p0, MMQ p1, int split) {
    constexpr int WAMAX = ((KB0 * OT0 > KB1 * OT1) ? KB0 * OT0 : KB1 * OT1) * 512;
    constexpr int KBMAX = (KB0 > KB1) ? KB0 : KB1;
    constexpr int XLSZ = 2 * KBMAX * 4 * 64 * 8;
    constexpr int OTMAX = (OT0 > OT1) ? OT0 : OT1;
    __shared__ __align__(16) unsigned short Wa[WAMAX];
    __shared__ __align__(16) unsigned short XL[XLSZ];
    __shared__ float sm1[4 * OTMAX * 16], sm2[4 * OTMAX * 16];
    if ((int)blockIdx.x < split)
        mm_body<KB0, OT0, NPH, NJL0, JXL0>(p0, blockIdx.x, Wa, XL, sm1, sm2);
    else
        mm_body<KB1, OT1, NPH, NJL1, JXL1>(p1, blockIdx.x - split, Wa, XL, sm1, sm2);
}

// ------------------------------------------------------------------
// layer-2 POOL GEMM with SWAPPED MFMA OPERANDS: mfma(X_frag, W_frag) so the
// output is transposed — each lane holds 4 j's of ONE o (o = lane&15).
// Max-pool over j then costs 3 in-lane fmax + 2 shfl_xor.
// Phase = 128 j; wave owns 32 j (= one ns=32 group -> in-wave pooling).
template <int KB, int OT, int NPH, int NSPOOL, int NJL, int JXL>
__device__ __forceinline__ void mmp_body(const MMQ P, int bx,
                                         unsigned short* Wa, unsigned short* XL,
                                         float* sm1, float* sm2) {
    constexpr int KB4 = KB * 4;
    const int oy = bx >> JXL;
    const int jxr = bx & ((1 << JXL) - 1);
    const int jx = ((jxr & 7) << (JXL - 3)) | (jxr >> 3);
    const int tid = threadIdx.x;
    const int lane = tid & 63;
    const int wid = tid >> 6;
    const int q = lane >> 4;
    const int jl = lane & 15;
    const int oybase = oy * OT * 16;
    const int jbase = jx * (NPH * 128);

    auto STAGE = [&](int buf, int p) {
        #pragma unroll
        for (int s0 = 0; s0 < 2 * KB; ++s0) {
            int s = wid + 4 * s0;
            int chunk = s >> 1;
            int half = s & 1;
            const unsigned short* gsrc =
                P.Xp + ((size_t)((chunk << NJL) + jbase + p * 128 + half * 64 + lane)) * 8;
            unsigned short* ldst = XL + ((size_t)((buf * KB4 + chunk) * 128 + half * 64)) * 8;
            __builtin_amdgcn_global_load_lds((gk_gvoid*)gsrc, (gk_svoid*)ldst, 16, 0, 0);
        }
    };

    STAGE(0, 0);

    // W staging with BN scale folded
    for (int s = tid; s < KB * OT * 64; s += 256) {
        int kb = s / (OT * 64);
        int r = s - kb * (OT * 64);
        int ot = r >> 6;
        int sl = r & 63;
        int o = oybase + ot * 16 + (sl & 15);
        int cbase = kb * 32 + (sl >> 4) * 8;
        unsigned int pk[4];
        #pragma unroll
        for (int e2 = 0; e2 < 4; ++e2) {
            int c0 = cbase + e2 * 2, c1 = c0 + 1;
            float w0 = (c0 < P.cin) ? P.W[(size_t)o * P.cin + c0] * P.ssin[c0 * 2 + 0] : 0.f;
            float w1 = (c1 < P.cin) ? P.W[(size_t)o * P.cin + c1] * P.ssin[c1 * 2 + 0] : 0.f;
            pk[e2] = (unsigned int)f2bf(w0) | ((unsigned int)f2bf(w1) << 16);
        }
        *(uint4*)&Wa[(size_t)s * 8] = make_uint4(pk[0], pk[1], pk[2], pk[3]);
    }
    __syncthreads();

    bf16x8 a[KB][OT];
    #pragma unroll
    for (int kb = 0; kb < KB; ++kb)
        #pragma unroll
        for (int ot = 0; ot < OT; ++ot)
            a[kb][ot] = *(const bf16x8*)&Wa[((kb * OT + ot) * 64 + lane) * 8];

    float tt[KB][8];
    #pragma unroll
    for (int kb = 0; kb < KB; ++kb)
        #pragma unroll
        for (int e = 0; e < 8; ++e) {
            int c = kb * 32 + q * 8 + e;
            tt[kb][e] = (c < P.cin) ? P.ssin[c * 2 + 1] : 0.f;
        }

    float s1_[OT][4], s2_[OT][4];
    #pragma unroll
    for (int ot = 0; ot < OT; ++ot)
        #pragma unroll
        for (int r = 0; r < 4; ++r) { s1_[ot][r] = 0.f; s2_[ot][r] = 0.f; }

    #pragma unroll
    for (int p = 0; p < NPH; ++p) {
        if (p + 1 < NPH) STAGE((p + 1) & 1, p + 1);
        const int buf = p & 1;
        float pm[2][OT];

        #pragma unroll
        for (int t2 = 0; t2 < 2; ++t2) {
            f32x4 acc[OT];
            #pragma unroll
            for (int ot = 0; ot < OT; ++ot) acc[ot] = (f32x4){0.f, 0.f, 0.f, 0.f};

            #pragma unroll
            for (int kb = 0; kb < KB; ++kb) {
                bf16x8 bf = *(const bf16x8*)&XL[((size_t)((buf * KB4 + kb * 4 + q) * 128 +
                                                          wid * 32 + t2 * 16 + jl)) * 8];
                union { bf16x8 v; unsigned int u[4]; } in, outp;
                in.v = bf;
                #pragma unroll
                for (int wd = 0; wd < 4; ++wd) {
                    float lo = __uint_as_float(in.u[wd] << 16);
                    float hi = __uint_as_float(in.u[wd] & 0xffff0000u);
                    lo = fmaxf(lo + tt[kb][2 * wd], 0.f);
                    hi = fmaxf(hi + tt[kb][2 * wd + 1], 0.f);
                    outp.u[wd] = cvt_pk(lo, hi);
                }
                bf = outp.v;
                #pragma unroll
                for (int ot = 0; ot < OT; ++ot)
                    acc[ot] = __builtin_amdgcn_mfma_f32_16x16x32_bf16(bf, a[kb][ot], acc[ot], 0, 0, 0);
            }

            #pragma unroll
            for (int ot = 0; ot < OT; ++ot) {
                float mx = fmaxf(fmaxf(acc[ot][0], acc[ot][1]), fmaxf(acc[ot][2], acc[ot][3]));
                #pragma unroll
                for (int r = 0; r < 4; ++r) {
                    float v = acc[ot][r];
                    s1_[ot][r] += v;
                    s2_[ot][r] = fmaf(v, v, s2_[ot][r]);
                }
                mx = fmaxf(mx, __shfl_xor(mx, 16));
                mx = fmaxf(mx, __shfl_xor(mx, 32));
                pm[t2][ot] = mx;
            }
        }

        int j0 = jbase + p * 128 + wid * 32;
        if (NSPOOL == 32) {
            if (lane < 16) {
                int bm = j0 >> 5;
                #pragma unroll
                for (int ot = 0; ot < OT; ++ot)
                    P.Ymax[(size_t)bm * 128 + oybase + ot * 16 + jl] = fmaxf(pm[0][ot], pm[1][ot]);
            }
        } else {
            if (lane < 16) {
                int bm0 = j0 >> 4;
                #pragma unroll
                for (int t2 = 0; t2 < 2; ++t2)
                    #pragma unroll
                    for (int ot = 0; ot < OT; ++ot)
                        P.Ymax[(size_t)(bm0 + t2) * 128 + oybase + ot * 16 + jl] = pm[t2][ot];
            }
        }
        __syncthreads();
    }

    #pragma unroll
    for (int ot = 0; ot < OT; ++ot) {
        float v1 = s1_[ot][0] + s1_[ot][1] + s1_[ot][2] + s1_[ot][3];
        float v2 = s2_[ot][0] + s2_[ot][1] + s2_[ot][2] + s2_[ot][3];
        v1 += __shfl_xor(v1, 16); v2 += __shfl_xor(v2, 16);
        v1 += __shfl_xor(v1, 32); v2 += __shfl_xor(v2, 32);
        if (lane < 16) {
            sm1[wid * (OT * 16) + ot * 16 + jl] = v1;
            sm2[wid * (OT * 16) + ot * 16 + jl] = v2;
        }
    }
    __syncthreads();
    for (int o = tid; o < OT * 16; o += 256) {
        float a1 = sm1[o] + sm1[OT * 16 + o] + sm1[2 * OT * 16 + o] + sm1[3 * OT * 16 + o];
        float a2 = sm2[o] + sm2[OT * 16 + o] + sm2[2 * OT * 16 + o] + sm2[3 * OT * 16 + o];
        P.pS[(size_t)(oybase + o) * PST + jx] = a1;
        P.pS2[(size_t)(oybase + o) * PST + jx] = a2;
    }
}

template <int KB0, int OT0, int NJL0, int NSP0, int JXL0,
          int KB1, int OT1, int NJL1, int NSP1, int JXL1, int NPH>
__global__ __launch_bounds__(256) void k_mmp(MMQ p0, MMQ p1, int split) {
    constexpr int WAMAX = ((KB0 * OT0 > KB1 * OT1) ? KB0 * OT0 : KB1 * OT1) * 512;
    constexpr int KBMAX = (KB0 > KB1) ? KB0 : KB1;
    constexpr int XLSZ = 2 * KBMAX * 4 * 128 * 8;
    constexpr int OTMAX = (OT0 > OT1) ? OT0 : OT1;
    __shared__ __align__(16) unsigned short Wa[WAMAX];
    __shared__ __align__(16) unsigned short XL[XLSZ];
    __shared__ float sm1[4 * OTMAX * 16], sm2[4 * OTMAX * 16];
    if ((int)blockIdx.x < split)
        mmp_body<KB0, OT0, NPH, NSP0, NJL0, JXL0>(p0, blockIdx.x, Wa, XL, sm1, sm2);
    else
        mmp_body<KB1, OT1, NPH, NSP1, NJL1, JXL1>(p1, blockIdx.x - split, Wa, XL, sm1, sm2);
}

// ------------------------------------------------------------------
// merged fin.  mode 0: ss = (scale, shift/scale); mode 1: ss = (scale, shift).
__global__ __launch_bounds__(64) void k_fin2(const float* __restrict__ pSa, const float* __restrict__ pS2a,
                                             const float* __restrict__ ga, const float* __restrict__ ba,
                                             float* __restrict__ ssa, int ca, int gxa, float invNa,
                                             const float* __restrict__ pSb, const float* __restrict__ pS2b,
                                             const float* __restrict__ gb, const float* __restrict__ bbv,
                                             float* __restrict__ ssb, int gxb, float invNb, int mode) {
    int o = blockIdx.x;
    const float *pS, *pS2, *g, *bt;
    float* ss;
    int gx;
    float invN;
    if (o < ca) { pS = pSa; pS2 = pS2a; g = ga; bt = ba; ss = ssa; gx = gxa; invN = invNa; }
    else { o -= ca; pS = pSb; pS2 = pS2b; g = gb; bt = bbv; ss = ssb; gx = gxb; invN = invNb; }
    int l = threadIdx.x;
    float s = 0.f, s2 = 0.f;
    for (int i = l; i < gx; i += 64) {
        s += pS[(size_t)o * PST + i];
        s2 += pS2[(size_t)o * PST + i];
    }
    #pragma unroll
    for (int off = 1; off < 64; off <<= 1) {
        s += __shfl_xor(s, off, 64);
        s2 += __shfl_xor(s2, off, 64);
    }
    if (l == 0) {
        float mean = s * invN;
        float var = s2 * invN - mean * mean;
        float scale = g[o] / sqrtf(var + 1e-5f);
        float shift = bt[o] - mean * scale;
        ss[o * 2 + 0] = scale;
        ss[o * 2 + 1] = mode ? shift : shift / scale;
    }
}

// ------------------------------------------------------------------
__global__ __launch_bounds__(256) void k_poolfin2(const float* __restrict__ Ymax0, const float* __restrict__ ss0,
                                                  const float* __restrict__ Ymax1, const float* __restrict__ ss1,
                                                  float* __restrict__ out) {
    __shared__ float T[128][65];
    int blk = blockIdx.x;
    const float* Ymax;
    const float* ss;
    int o_off;
    if (blk < 64) { Ymax = Ymax0; ss = ss0; o_off = 0; }
    else { blk -= 64; Ymax = Ymax1; ss = ss1; o_off = 128; }
    int b = blk >> 4, mc = blk & 15;
    int bm0 = b * M_ + mc * 64;
    for (int s = threadIdx.x; s < 64 * 32; s += 256) {
        int row = s >> 5;
        int c4 = s & 31;
        float4 v = *(const float4*)&Ymax[(size_t)(bm0 + row) * 128 + c4 * 4];
        T[c4 * 4 + 0][row] = v.x;
        T[c4 * 4 + 1][row] = v.y;
        T[c4 * 4 + 2][row] = v.z;
        T[c4 * 4 + 3][row] = v.w;
    }
    __syncthreads();
    for (int s = threadIdx.x; s < 128 * 16; s += 256) {
        int o = s >> 4, m4 = s & 15;
        float scv = ss[o * 2 + 0], shv = ss[o * 2 + 1];
        float4 v = make_float4(T[o][m4 * 4], T[o][m4 * 4 + 1], T[o][m4 * 4 + 2], T[o][m4 * 4 + 3]);
        v.x = fmaxf(fmaf(v.x, scv, shv), 0.f);
        v.y = fmaxf(fmaf(v.y, scv, shv), 0.f);
        v.z = fmaxf(fmaf(v.z, scv, shv), 0.f);
        v.w = fmaxf(fmaf(v.w, scv, shv), 0.f);
        *(float4*)&out[OUT_XYZ_ELEMS + ((size_t)(b * 256 + o_off + o)) * M_ + mc * 64 + m4 * 4] = v;
    }
}

// ------------------------------------------------------------------
extern "C" void kernel_launch(void* const* d_in, const int* in_sizes, int n_in,
                              void* d_out, int out_size, void* d_ws, size_t ws_size,
                              hipStream_t stream) {
    const float* xyz = (const float*)d_in[0];
    const float* feats = (const float*)d_in[1];
    const int* inds = (const int*)d_in[2];
    const float* w[2][3];
    const float* gg[2][3];
    const float* bb[2][3];
    int k = 3;
    for (int i = 0; i < 2; ++i)
        for (int l = 0; l < 3; ++l) {
            w[i][l] = (const float*)d_in[k++];
            gg[i][l] = (const float*)d_in[k++];
            bb[i][l] = (const float*)d_in[k++];
        }
    float* out = (float*)d_out;

    const int Nj0 = B_ * M_ * 16;  // 65536 = 1<<16
    const int Nj1 = B_ * M_ * 32;  // 131072 = 1<<17

    unsigned short* Z0 = (unsigned short*)d_ws;
    unsigned short* Z1 = Z0 + (size_t)B_ * N_ * 64;
    unsigned short* bufB0 = Z1 + (size_t)B_ * N_ * 64;
    unsigned short* bufA0 = bufB0 + (size_t)8 * Nj0 * 8;
    unsigned short* bufB1 = bufA0 + (size_t)12 * Nj0 * 8;
    unsigned short* bufA1 = bufB1 + (size_t)8 * Nj1 * 8;
    float* Ymax0 = (float*)(bufA1 + (size_t)12 * Nj1 * 8);
    float* Ymax1 = Ymax0 + (size_t)B_ * M_ * 128;
    float* pS0 = Ymax1 + (size_t)B_ * M_ * 128;
    float* pS2_0 = pS0 + (size_t)128 * PST;
    float* pS1 = pS2_0 + (size_t)128 * PST;
    float* pS2_1 = pS1 + (size_t)128 * PST;
    float* ss0 = pS2_1 + (size_t)128 * PST;
    float* ss1 = ss0 + 256;
    int* idx0 = (int*)(ss1 + 256);
    int* idx1 = idx0 + Nj0;
    ushort4* rel0 = (ushort4*)(idx1 + Nj1);
    ushort4* rel1 = rel0 + Nj0;

    const float inv0 = 1.f / Nj0, inv1 = 1.f / Nj1;

    // 1) prep: transpose+dense-L0 (blocks 0-1023) and dual ball (1024-2047)
    k_prep<<<2048, 256, 0, stream>>>(xyz, feats, inds, w[0][0], w[1][0], Z0, Z1, out,
                                     idx0, rel0, idx1, rel1,
                                     (float)(0.4 * 0.4), (float)(0.8 * 0.8));

    // 2) gather + xyz-add + stats -> bufB  (TPW=4: 256 j/block)
    GQ g0{}, g1{};
    g0.W = w[0][0]; g0.Z = Z0; g0.idxb = idx0; g0.relb = rel0;
    g0.Xp = bufB0; g0.pS = pS0; g0.pS2 = pS2_0;
    g1.W = w[1][0]; g1.Z = Z1; g1.idxb = idx1; g1.relb = rel1;
    g1.Xp = bufB1; g1.pS = pS1; g1.pS2 = pS2_1;
    k_gath2<<<768, 256, 0, stream>>>(g0, g1, 256);
    k_fin2<<<128, 64, 0, stream>>>(pS0, pS2_0, gg[0][0], bb[0][0], ss0, 64, 256, inv0,
                                   pS1, pS2_1, gg[1][0], bb[1][0], ss1, 512, inv1, 0);

    // 3) layer1: NPH=4 (256 j/block).  s0: KB2 OT4 (64ch, 256 jx);
    //            s1: KB2 OT6 (96ch, 512 jx).
    MMQ b0{}, b1{};
    b0.W = w[0][1]; b0.Xp = bufB0; b0.ssin = ss0; b0.Yp = bufA0;
    b0.pS = pS0; b0.pS2 = pS2_0; b0.cin = 64;
    b1.W = w[1][1]; b1.Xp = bufB1; b1.ssin = ss1; b1.Yp = bufA1;
    b1.pS = pS1; b1.pS2 = pS2_1; b1.cin = 64;
    k_mm2<2, 4, 16, 8,  2, 6, 17, 9,  4>
        <<<768, 256, 0, stream>>>(b0, b1, 256);
    k_fin2<<<160, 64, 0, stream>>>(pS0, pS2_0, gg[0][1], bb[0][1], ss0, 64, 256, inv0,
                                   pS1, pS2_1, gg[1][1], bb[1][1], ss1, 512, inv1, 0);

    // 4) layer2 POOL (swapped-operand): NPH=4, 512 j/block, s1 FIRST.
    //    s1: KB3 OT4 oy2 (256 jx -> 512 blocks); s0: KB2 OT4 oy2 (128 jx -> 256).
    MMQ c0{}, c1{};
    c0.W = w[0][2]; c0.Xp = bufA0; c0.ssin = ss0; c0.Ymax = Ymax0;
    c0.pS = pS0; c0.pS2 = pS2_0; c0.cin = 64;
    c1.W = w[1][2]; c1.Xp = bufA1; c1.ssin = ss1; c1.Ymax = Ymax1;
    c1.pS = pS1; c1.pS2 = pS2_1; c1.cin = 96;
    k_mmp<3, 4, 17, 32, 8,  2, 4, 16, 16, 7,  4>
        <<<768, 256, 0, stream>>>(c1, c0, 512);
    k_fin2<<<256, 64, 0, stream>>>(pS0, pS2_0, gg[0][2], bb[0][2], ss0, 128, 128, inv0,
                                   pS1, pS2_1, gg[1][2], bb[1][2], ss1, 256, inv1, 1);

    // 5) final BN+ReLU + transpose
    k_poolfin2<<<128, 256, 0, stream>>>(Ymax0, ss0, Ymax1, ss1, out);
}